// Round 3
// baseline (1088.730 us; speedup 1.0000x reference)
//
#include <hip/hip_runtime.h>

constexpr int H = 64;
constexpr int PAD = 68;     // LDS row stride (floats): 16B-aligned, rotates banks
constexpr int BSH = 6;      // 64 nodes per bucket
constexpr int EPB = 4096;   // edges per binning block
constexpr int EPT = EPB / 256;  // 16 edges per thread

// ---------------- encode: h[n][j] = x[n] * ne_w[j] + ne_b[j] ----------------
__global__ __launch_bounds__(256) void encode_kernel(
    const float* __restrict__ x, const float* __restrict__ nw,
    const float* __restrict__ nb, float* __restrict__ hout, int N)
{
    int idx = blockIdx.x * 256 + threadIdx.x;
    if (idx >= N * 16) return;
    int n = idx >> 4, c = idx & 15;
    float xv = x[n];
    float4 w = ((const float4*)nw)[c];
    float4 b = ((const float4*)nb)[c];
    float4 r;
    r.x = fmaf(xv, w.x, b.x);
    r.y = fmaf(xv, w.y, b.y);
    r.z = fmaf(xv, w.z, b.z);
    r.w = fmaf(xv, w.w, b.w);
    ((float4*)hout)[idx] = r;
}

// ---------------- bucket histogram (LDS-aggregated) ----------------
__global__ __launch_bounds__(256) void bhist_kernel(
    const int* __restrict__ ei, int* __restrict__ ghist, int E, int NB)
{
    extern __shared__ int lh[];               // NB ints
    for (int b = threadIdx.x; b < NB; b += 256) lh[b] = 0;
    __syncthreads();
    int k0 = blockIdx.x * EPB;
#pragma unroll
    for (int i = 0; i < EPT; ++i) {
        int k = k0 + threadIdx.x + i * 256;
        if (k < E) atomicAdd(&lh[ei[E + k] >> BSH], 1);
    }
    __syncthreads();
    for (int b = threadIdx.x; b < NB; b += 256)
        if (lh[b]) atomicAdd(&ghist[b], lh[b]);
}

// ---------------- single-block exclusive scan; also seeds gcur ----------------
__global__ __launch_bounds__(256) void bscan_kernel(
    const int* __restrict__ ghist, int* __restrict__ off,
    int* __restrict__ gcur, int NB)
{
    __shared__ int part[256];
    int t = threadIdx.x;
    const int C = (NB + 255) / 256;           // bins per thread (<=16)
    int loc[16];
    int s = 0;
    for (int j = 0; j < C; ++j) {
        int idx = t * C + j;
        int v = (idx < NB) ? ghist[idx] : 0;
        loc[j] = s; s += v;
    }
    part[t] = s;
    __syncthreads();
    for (int d = 1; d < 256; d <<= 1) {
        int x = (t >= d) ? part[t - d] : 0;
        __syncthreads();
        part[t] += x;
        __syncthreads();
    }
    int base = part[t] - s;                   // exclusive block prefix
    for (int j = 0; j < C; ++j) {
        int idx = t * C + j;
        if (idx < NB) { int v = base + loc[j]; off[idx] = v; gcur[idx] = v; }
    }
    if (t == 255) off[NB] = part[255];
}

// ---------------- block-aggregated bin scatter ----------------
// Counting-sort 4096 edges into 64-node buckets in LDS, reserve contiguous
// global runs per (block,bucket), write records in sorted order (coalesced,
// line-merged). Record: (dstLocal<<17 | src, ea) -- src < 2^17, dl < 64.
__global__ __launch_bounds__(256) void binscatter_kernel(
    const int* __restrict__ ei, const float* __restrict__ eattr,
    int* __restrict__ gcur, int2* __restrict__ bed, int E, int NB)
{
    extern __shared__ int smem[];
    int2* stage = (int2*)smem;                // EPB int2
    int*  A     = smem + 2 * EPB;             // NB+1: hist -> exclusive offsets
    int*  B     = A + NB + 1;                 // NB: cursor -> (gbase - A[b])
    int*  part  = B + NB;                     // 256
    int t = threadIdx.x;
    int k0 = blockIdx.x * EPB;

    for (int b = t; b < NB + 1; b += 256) A[b] = 0;
    __syncthreads();

    int dsts[EPT];
#pragma unroll
    for (int i = 0; i < EPT; ++i) {
        int k = k0 + t + i * 256;
        dsts[i] = (k < E) ? ei[E + k] : -1;
        if (dsts[i] >= 0) atomicAdd(&A[dsts[i] >> BSH], 1);
    }
    __syncthreads();

    // in-place exclusive scan of A[0..NB-1]
    const int C = (NB + 255) / 256;
    int loc[16];
    int s = 0;
    for (int j = 0; j < C; ++j) {
        int idx = t * C + j;
        int v = (idx < NB) ? A[idx] : 0;
        loc[j] = s; s += v;
    }
    part[t] = s;
    __syncthreads();
    for (int d = 1; d < 256; d <<= 1) {
        int x = (t >= d) ? part[t - d] : 0;
        __syncthreads();
        part[t] += x;
        __syncthreads();
    }
    int base = part[t] - s;
    int tot = part[255];
    for (int j = 0; j < C; ++j) {
        int idx = t * C + j;
        if (idx < NB) { int e = base + loc[j]; A[idx] = e; B[idx] = e; }
    }
    if (t == 255) A[NB] = tot;
    __syncthreads();

    // stage records at their sorted local slot
#pragma unroll
    for (int i = 0; i < EPT; ++i) {
        if (dsts[i] >= 0) {
            int k = k0 + t + i * 256;
            int b = dsts[i] >> BSH;
            int dl = dsts[i] & 63;
            int slot = atomicAdd(&B[b], 1);
            stage[slot] = make_int2((dl << 17) | ei[k], __float_as_int(eattr[k]));
        }
    }
    __syncthreads();

    // reserve global runs: B[b] := gbase - A[b]
    for (int b = t; b < NB; b += 256) {
        int c0 = A[b], c1 = B[b];
        if (c1 > c0) B[b] = atomicAdd(&gcur[b], c1 - c0) - c0;
    }
    __syncthreads();

    // write out: thread t owns slots [t*EPT, t*EPT+EPT)
    int s0 = t * EPT;
    int lo = 0, hi = NB;
    while (hi - lo > 1) { int mid = (lo + hi) >> 1; if (A[mid] <= s0) lo = mid; else hi = mid; }
    int b = lo;
#pragma unroll
    for (int i = 0; i < EPT; ++i) {
        int sl = s0 + i;
        if (sl >= tot) break;
        while (sl >= A[b + 1]) ++b;
        bed[B[b] + sl] = stage[sl];
    }
}

// ---------------- aggregate: z[n] = h[n] + sum relu(h[src] + ea*ew + eb) ----
// one block per 64-node bucket; 4 waves stream the bucket's edge records
__global__ __launch_bounds__(256) void agg_kernel(
    const float* __restrict__ h, const int2* __restrict__ bed,
    const int* __restrict__ off, const float* __restrict__ ew,
    const float* __restrict__ eb, float* __restrict__ z, int N)
{
    __shared__ float acc[64 * PAD];
    int t = threadIdx.x;
    for (int i = t; i < 64 * PAD; i += 256) acc[i] = 0.f;
    int lane = t & 63, wid = t >> 6;
    float wj = ew[lane], bj = eb[lane];
    int b = blockIdx.x;
    int e0 = off[b], e1 = off[b + 1];
    __syncthreads();

    int e = e0 + wid;
    for (; e + 4 < e1; e += 8) {
        int2 r0 = bed[e];
        int2 r1 = bed[e + 4];
        float m0 = fmaxf(fmaf(__int_as_float(r0.y), wj, bj)
                         + h[(size_t)(r0.x & 0x1FFFF) * H + lane], 0.f);
        float m1 = fmaxf(fmaf(__int_as_float(r1.y), wj, bj)
                         + h[(size_t)(r1.x & 0x1FFFF) * H + lane], 0.f);
        atomicAdd(&acc[(r0.x >> 17) * PAD + lane], m0);
        atomicAdd(&acc[(r1.x >> 17) * PAD + lane], m1);
    }
    for (; e < e1; e += 4) {
        int2 r = bed[e];
        float m = fmaxf(fmaf(__int_as_float(r.y), wj, bj)
                        + h[(size_t)(r.x & 0x1FFFF) * H + lane], 0.f);
        atomicAdd(&acc[(r.x >> 17) * PAD + lane], m);
    }
    __syncthreads();

    int nl = t >> 2, jc = (t & 3) * 16;
    int n = b * 64 + nl;
    if (n < N) {
#pragma unroll
        for (int m = 0; m < 4; ++m) {
            float4 hv = *(const float4*)(h + (size_t)n * H + jc + m * 4);
            float4 av = *(const float4*)(acc + nl * PAD + jc + m * 4);
            float4 r;
            r.x = hv.x + av.x; r.y = hv.y + av.y;
            r.z = hv.z + av.z; r.w = hv.w + av.w;
            *(float4*)(z + (size_t)n * H + jc + m * 4) = r;
        }
    }
}

// ---------------- per 64-node tile MLP ----------------
__global__ __launch_bounds__(256) void mlp_kernel(
    const float* __restrict__ z, const float* __restrict__ w1,
    const float* __restrict__ b1, const float* __restrict__ w2,
    const float* __restrict__ b2, float* __restrict__ out, int N)
{
    __shared__ float zT[H * PAD];
    __shared__ float wS[H * PAD];
    int tid = threadIdx.x;
    int nb = blockIdx.x * 64;

    {
        int i  = tid >> 2;
        int jc = (tid & 3) * 16;
        const float4* s = (const float4*)(w1 + i * H + jc);
        float4* d = (float4*)(wS + i * PAD + jc);
        d[0] = s[0]; d[1] = s[1]; d[2] = s[2]; d[3] = s[3];
    }
    {
        int nl = tid >> 2;
        int n  = nb + nl;
        int ic = (tid & 3) * 16;
        if (n < N) {
#pragma unroll
            for (int m = 0; m < 4; ++m) {
                float4 zv = *(const float4*)(z + (size_t)n * H + ic + m * 4);
                zT[(ic + m * 4 + 0) * PAD + nl] = zv.x;
                zT[(ic + m * 4 + 1) * PAD + nl] = zv.y;
                zT[(ic + m * 4 + 2) * PAD + nl] = zv.z;
                zT[(ic + m * 4 + 3) * PAD + nl] = zv.w;
            }
        } else {
#pragma unroll
            for (int m = 0; m < 4; ++m)
#pragma unroll
                for (int q = 0; q < 4; ++q)
                    zT[(ic + m * 4 + q) * PAD + nl] = 0.f;
        }
    }
    __syncthreads();

    int tj = tid & 15, tn = tid >> 4;
    int j0 = tj * 4, n0 = tn * 4;

    float acc[4][4] = {};
#pragma unroll 4
    for (int i = 0; i < H; ++i) {
        float4 a = *(const float4*)(zT + i * PAD + n0);
        float4 b = *(const float4*)(wS + i * PAD + j0);
        float av[4] = {a.x, a.y, a.z, a.w};
        float bv[4] = {b.x, b.y, b.z, b.w};
#pragma unroll
        for (int p = 0; p < 4; ++p)
#pragma unroll
            for (int q = 0; q < 4; ++q)
                acc[p][q] = fmaf(av[p], bv[q], acc[p][q]);
    }
    float4 bb1 = *(const float4*)(b1 + j0);
    float u[4][4];
#pragma unroll
    for (int p = 0; p < 4; ++p) {
        u[p][0] = fmaxf(acc[p][0] + bb1.x, 0.f);
        u[p][1] = fmaxf(acc[p][1] + bb1.y, 0.f);
        u[p][2] = fmaxf(acc[p][2] + bb1.z, 0.f);
        u[p][3] = fmaxf(acc[p][3] + bb1.w, 0.f);
    }
    __syncthreads();

#pragma unroll
    for (int p = 0; p < 4; ++p)
#pragma unroll
        for (int q = 0; q < 4; ++q)
            zT[(j0 + q) * PAD + (n0 + p)] = u[p][q];
    {
        int i  = tid >> 2;
        int jc = (tid & 3) * 16;
        const float4* s = (const float4*)(w2 + i * H + jc);
        float4* d = (float4*)(wS + i * PAD + jc);
        d[0] = s[0]; d[1] = s[1]; d[2] = s[2]; d[3] = s[3];
    }
    __syncthreads();

    float acc2[4][4] = {};
#pragma unroll 4
    for (int i = 0; i < H; ++i) {
        float4 a = *(const float4*)(zT + i * PAD + n0);
        float4 b = *(const float4*)(wS + i * PAD + j0);
        float av[4] = {a.x, a.y, a.z, a.w};
        float bv[4] = {b.x, b.y, b.z, b.w};
#pragma unroll
        for (int p = 0; p < 4; ++p)
#pragma unroll
            for (int q = 0; q < 4; ++q)
                acc2[p][q] = fmaf(av[p], bv[q], acc2[p][q]);
    }
    float4 bb2 = *(const float4*)(b2 + j0);
#pragma unroll
    for (int p = 0; p < 4; ++p) {
        int n = nb + n0 + p;
        if (n < N) {
            float4 r;
            r.x = fmaxf(acc2[p][0] + bb2.x, 0.f);
            r.y = fmaxf(acc2[p][1] + bb2.y, 0.f);
            r.z = fmaxf(acc2[p][2] + bb2.z, 0.f);
            r.w = fmaxf(acc2[p][3] + bb2.w, 0.f);
            *(float4*)(out + (size_t)n * H + j0) = r;
        }
    }
}

// ---------------- mean pool (batch sorted) ----------------
__global__ __launch_bounds__(64) void pool_kernel(
    const float* __restrict__ h, const int* __restrict__ batch,
    float* __restrict__ sums, float* __restrict__ counts, int N)
{
    int lane = threadIdx.x;
    int start = blockIdx.x * 256;
    if (start >= N) return;
    int end = start + 256; if (end > N) end = N;
    int cur = batch[start];
    float acc = 0.f;
    int cnt = 0;
    for (int n = start; n < end; ++n) {
        int g = batch[n];
        if (g != cur) {
            atomicAdd(sums + cur * H + lane, acc);
            if (lane == 0) atomicAdd(counts + cur, (float)cnt);
            acc = 0.f; cnt = 0; cur = g;
        }
        acc += h[(size_t)n * H + lane];
        cnt++;
    }
    atomicAdd(sums + cur * H + lane, acc);
    if (lane == 0) atomicAdd(counts + cur, (float)cnt);
}

__global__ void div_kernel(const float* __restrict__ sums,
                           const float* __restrict__ counts,
                           float* __restrict__ out)
{
    int g = blockIdx.x, j = threadIdx.x;
    out[g * H + j] = sums[g * H + j] / fmaxf(counts[g], 1.0f);
}

extern "C" void kernel_launch(void* const* d_in, const int* in_sizes, int n_in,
                              void* d_out, int out_size, void* d_ws, size_t ws_size,
                              hipStream_t stream)
{
    const float* x     = (const float*)d_in[0];
    const int*   ei    = (const int*)d_in[1];
    const float* eattr = (const float*)d_in[2];
    const int*   batch = (const int*)d_in[3];
    const float* ne_w  = (const float*)d_in[4];
    const float* ne_b  = (const float*)d_in[5];
    const float* ee_w  = (const float*)d_in[6];
    const float* ee_b  = (const float*)d_in[7];
    const float* c1w1  = (const float*)d_in[8];
    const float* c1b1  = (const float*)d_in[9];
    const float* c1w2  = (const float*)d_in[10];
    const float* c1b2  = (const float*)d_in[11];
    const float* c2w1  = (const float*)d_in[12];
    const float* c2b1  = (const float*)d_in[13];
    const float* c2w2  = (const float*)d_in[14];
    const float* c2b2  = (const float*)d_in[15];

    const int N = in_sizes[0];
    const int E = in_sizes[2];
    const int NB = (N + 63) >> BSH;          // 64-node buckets

    // ---- workspace ----
    float* h      = (float*)d_ws;            // N*H
    float* z      = h + (size_t)N * H;       // N*H
    float* sums   = z + (size_t)N * H;       // 64*H
    float* counts = sums + 64 * H;           // 64
    int*   ghist  = (int*)(counts + 64);     // NB
    int*   off    = ghist + NB;              // NB+1
    int*   gcur   = off + NB + 1;            // NB
    uintptr_t p = (uintptr_t)(gcur + NB);
    p = (p + 15) & ~(uintptr_t)15;
    int2*  bed    = (int2*)p;                // E records

    const int eGrid = (E + EPB - 1) / EPB;
    const int aggGrid = NB;
    const int mlpGrid = (N + 63) / 64;

    size_t histLds = (size_t)NB * sizeof(int);
    size_t scatLds = (size_t)(2 * EPB + (NB + 1) + NB + 256) * sizeof(int);

    encode_kernel<<<(N * 16 + 255) / 256, 256, 0, stream>>>(x, ne_w, ne_b, h, N);

    // ---- bucket build (once) ----
    hipMemsetAsync(ghist, 0, (size_t)NB * sizeof(int), stream);
    bhist_kernel<<<eGrid, 256, histLds, stream>>>(ei, ghist, E, NB);
    bscan_kernel<<<1, 256, 0, stream>>>(ghist, off, gcur, NB);
    binscatter_kernel<<<eGrid, 256, scatLds, stream>>>(ei, eattr, gcur, bed, E, NB);

    // ---- layer 1 ----
    agg_kernel<<<aggGrid, 256, 0, stream>>>(h, bed, off, ee_w, ee_b, z, N);
    mlp_kernel<<<mlpGrid, 256, 0, stream>>>(z, c1w1, c1b1, c1w2, c1b2, h, N);

    // ---- layer 2 ----
    agg_kernel<<<aggGrid, 256, 0, stream>>>(h, bed, off, ee_w, ee_b, z, N);
    mlp_kernel<<<mlpGrid, 256, 0, stream>>>(z, c2w1, c2b1, c2w2, c2b2, h, N);

    // ---- mean pool ----
    hipMemsetAsync(sums, 0, (64 * H + 64) * sizeof(float), stream);
    pool_kernel<<<(N + 255) / 256, 64, 0, stream>>>(h, batch, sums, counts, N);
    div_kernel<<<64, 64, 0, stream>>>(sums, counts, (float*)d_out);
}

// Round 4
// 1078.447 us; speedup vs baseline: 1.0095x; 1.0095x over previous
//
#include <hip/hip_runtime.h>

constexpr int H = 64;
constexpr int PAD = 68;     // LDS row stride (floats): 16B-aligned, rotates banks
constexpr int BSH = 6;      // 64 nodes per bucket
constexpr int EPB = 4096;   // edges per binning block
constexpr int EPT = EPB / 256;  // 16 edges per thread

// ---------------- encode: h[n][j] = x[n] * ne_w[j] + ne_b[j] ----------------
__global__ __launch_bounds__(256) void encode_kernel(
    const float* __restrict__ x, const float* __restrict__ nw,
    const float* __restrict__ nb, float* __restrict__ hout, int N)
{
    int idx = blockIdx.x * 256 + threadIdx.x;
    if (idx >= N * 16) return;
    int n = idx >> 4, c = idx & 15;
    float xv = x[n];
    float4 w = ((const float4*)nw)[c];
    float4 b = ((const float4*)nb)[c];
    float4 r;
    r.x = fmaf(xv, w.x, b.x);
    r.y = fmaf(xv, w.y, b.y);
    r.z = fmaf(xv, w.z, b.z);
    r.w = fmaf(xv, w.w, b.w);
    ((float4*)hout)[idx] = r;
}

// ---------------- bucket histogram (LDS-aggregated) ----------------
__global__ __launch_bounds__(256) void bhist_kernel(
    const int* __restrict__ ei, int* __restrict__ ghist, int E, int NB)
{
    extern __shared__ int lh[];               // NB ints
    for (int b = threadIdx.x; b < NB; b += 256) lh[b] = 0;
    __syncthreads();
    int k0 = blockIdx.x * EPB;
#pragma unroll
    for (int i = 0; i < EPT; ++i) {
        int k = k0 + threadIdx.x + i * 256;
        if (k < E) atomicAdd(&lh[ei[E + k] >> BSH], 1);
    }
    __syncthreads();
    for (int b = threadIdx.x; b < NB; b += 256)
        if (lh[b]) atomicAdd(&ghist[b], lh[b]);
}

// ---------------- single-block exclusive scan; also seeds gcur ----------------
__global__ __launch_bounds__(256) void bscan_kernel(
    const int* __restrict__ ghist, int* __restrict__ off,
    int* __restrict__ gcur, int NB)
{
    __shared__ int part[256];
    int t = threadIdx.x;
    const int C = (NB + 255) / 256;
    int loc[16];
    int s = 0;
    for (int j = 0; j < C; ++j) {
        int idx = t * C + j;
        int v = (idx < NB) ? ghist[idx] : 0;
        loc[j] = s; s += v;
    }
    part[t] = s;
    __syncthreads();
    for (int d = 1; d < 256; d <<= 1) {
        int x = (t >= d) ? part[t - d] : 0;
        __syncthreads();
        part[t] += x;
        __syncthreads();
    }
    int base = part[t] - s;
    for (int j = 0; j < C; ++j) {
        int idx = t * C + j;
        if (idx < NB) { int v = base + loc[j]; off[idx] = v; gcur[idx] = v; }
    }
    if (t == 255) off[NB] = part[255];
}

// ---------------- block-aggregated bin scatter ----------------
// Record: (dstLocal<<17 | src, ea) -- src < 2^17, dl < 64.
__global__ __launch_bounds__(256) void binscatter_kernel(
    const int* __restrict__ ei, const float* __restrict__ eattr,
    int* __restrict__ gcur, int2* __restrict__ bed, int E, int NB)
{
    extern __shared__ int smem[];
    int2* stage = (int2*)smem;                // EPB int2
    int*  A     = smem + 2 * EPB;             // NB+1
    int*  B     = A + NB + 1;                 // NB
    int*  part  = B + NB;                     // 256
    int t = threadIdx.x;
    int k0 = blockIdx.x * EPB;

    for (int b = t; b < NB + 1; b += 256) A[b] = 0;
    __syncthreads();

    int dsts[EPT];
#pragma unroll
    for (int i = 0; i < EPT; ++i) {
        int k = k0 + t + i * 256;
        dsts[i] = (k < E) ? ei[E + k] : -1;
        if (dsts[i] >= 0) atomicAdd(&A[dsts[i] >> BSH], 1);
    }
    __syncthreads();

    const int C = (NB + 255) / 256;
    int loc[16];
    int s = 0;
    for (int j = 0; j < C; ++j) {
        int idx = t * C + j;
        int v = (idx < NB) ? A[idx] : 0;
        loc[j] = s; s += v;
    }
    part[t] = s;
    __syncthreads();
    for (int d = 1; d < 256; d <<= 1) {
        int x = (t >= d) ? part[t - d] : 0;
        __syncthreads();
        part[t] += x;
        __syncthreads();
    }
    int base = part[t] - s;
    int tot = part[255];
    for (int j = 0; j < C; ++j) {
        int idx = t * C + j;
        if (idx < NB) { int e = base + loc[j]; A[idx] = e; B[idx] = e; }
    }
    if (t == 255) A[NB] = tot;
    __syncthreads();

#pragma unroll
    for (int i = 0; i < EPT; ++i) {
        if (dsts[i] >= 0) {
            int k = k0 + t + i * 256;
            int b = dsts[i] >> BSH;
            int dl = dsts[i] & 63;
            int slot = atomicAdd(&B[b], 1);
            stage[slot] = make_int2((dl << 17) | ei[k], __float_as_int(eattr[k]));
        }
    }
    __syncthreads();

    for (int b = t; b < NB; b += 256) {
        int c0 = A[b], c1 = B[b];
        if (c1 > c0) B[b] = atomicAdd(&gcur[b], c1 - c0) - c0;
    }
    __syncthreads();

    int s0 = t * EPT;
    int lo = 0, hi = NB;
    while (hi - lo > 1) { int mid = (lo + hi) >> 1; if (A[mid] <= s0) lo = mid; else hi = mid; }
    int b = lo;
#pragma unroll
    for (int i = 0; i < EPT; ++i) {
        int sl = s0 + i;
        if (sl >= tot) break;
        while (sl >= A[b + 1]) ++b;
        bed[B[b] + sl] = stage[sl];
    }
}

// ---------------- aggregate v2: z[n] = h[n] + sum relu(h[src] + ea*ew + eb) ----
// 1024 threads (16 waves) per 64-node bucket. Each wave takes chunks of 8
// consecutive records: scalar (SGPR) record loads via readfirstlane'd base,
// 8 independent h[src] gathers in flight, then 8 LDS float atomics.
__global__ __launch_bounds__(1024, 8) void agg_kernel(
    const float* __restrict__ h, const int2* __restrict__ bed,
    const int* __restrict__ off, const float* __restrict__ ew,
    const float* __restrict__ eb, float* __restrict__ z, int N)
{
    __shared__ float acc[64 * PAD];
    int t = threadIdx.x;
    for (int i = t; i < 64 * PAD; i += 1024) acc[i] = 0.f;
    int lane = t & 63, wid = t >> 6;          // 16 waves
    float wj = ew[lane], bj = eb[lane];
    int b = blockIdx.x;
    int e0 = off[b], e1 = off[b + 1];
    __syncthreads();

    for (int c = wid;; c += 16) {
        int base = e0 + c * 8;
        if (base >= e1) break;
        if (base + 8 <= e1) {
            int bu = __builtin_amdgcn_readfirstlane(base);
            const int2* p = bed + bu;
            int2 r0 = p[0], r1 = p[1], r2 = p[2], r3 = p[3];
            int2 r4 = p[4], r5 = p[5], r6 = p[6], r7 = p[7];
            float h0 = h[(size_t)(r0.x & 0x1FFFF) * H + lane];
            float h1 = h[(size_t)(r1.x & 0x1FFFF) * H + lane];
            float h2 = h[(size_t)(r2.x & 0x1FFFF) * H + lane];
            float h3 = h[(size_t)(r3.x & 0x1FFFF) * H + lane];
            float h4 = h[(size_t)(r4.x & 0x1FFFF) * H + lane];
            float h5 = h[(size_t)(r5.x & 0x1FFFF) * H + lane];
            float h6 = h[(size_t)(r6.x & 0x1FFFF) * H + lane];
            float h7 = h[(size_t)(r7.x & 0x1FFFF) * H + lane];
            atomicAdd(&acc[(r0.x >> 17) * PAD + lane],
                      fmaxf(fmaf(__int_as_float(r0.y), wj, bj) + h0, 0.f));
            atomicAdd(&acc[(r1.x >> 17) * PAD + lane],
                      fmaxf(fmaf(__int_as_float(r1.y), wj, bj) + h1, 0.f));
            atomicAdd(&acc[(r2.x >> 17) * PAD + lane],
                      fmaxf(fmaf(__int_as_float(r2.y), wj, bj) + h2, 0.f));
            atomicAdd(&acc[(r3.x >> 17) * PAD + lane],
                      fmaxf(fmaf(__int_as_float(r3.y), wj, bj) + h3, 0.f));
            atomicAdd(&acc[(r4.x >> 17) * PAD + lane],
                      fmaxf(fmaf(__int_as_float(r4.y), wj, bj) + h4, 0.f));
            atomicAdd(&acc[(r5.x >> 17) * PAD + lane],
                      fmaxf(fmaf(__int_as_float(r5.y), wj, bj) + h5, 0.f));
            atomicAdd(&acc[(r6.x >> 17) * PAD + lane],
                      fmaxf(fmaf(__int_as_float(r6.y), wj, bj) + h6, 0.f));
            atomicAdd(&acc[(r7.x >> 17) * PAD + lane],
                      fmaxf(fmaf(__int_as_float(r7.y), wj, bj) + h7, 0.f));
        } else {
            for (int e = base; e < e1; ++e) {
                int2 r = bed[e];
                float m = fmaxf(fmaf(__int_as_float(r.y), wj, bj)
                                + h[(size_t)(r.x & 0x1FFFF) * H + lane], 0.f);
                atomicAdd(&acc[(r.x >> 17) * PAD + lane], m);
            }
        }
    }
    __syncthreads();

    // epilogue: z = h + acc  (1024 threads: one float4 each)
    int nl = t >> 4, jc = (t & 15) * 4;
    int n = b * 64 + nl;
    if (n < N) {
        float4 hv = *(const float4*)(h + (size_t)n * H + jc);
        float4 av = *(const float4*)(acc + nl * PAD + jc);
        float4 r;
        r.x = hv.x + av.x; r.y = hv.y + av.y;
        r.z = hv.z + av.z; r.w = hv.w + av.w;
        *(float4*)(z + (size_t)n * H + jc) = r;
    }
}

// ---------------- per 64-node tile MLP ----------------
__global__ __launch_bounds__(256) void mlp_kernel(
    const float* __restrict__ z, const float* __restrict__ w1,
    const float* __restrict__ b1, const float* __restrict__ w2,
    const float* __restrict__ b2, float* __restrict__ out, int N)
{
    __shared__ float zT[H * PAD];
    __shared__ float wS[H * PAD];
    int tid = threadIdx.x;
    int nb = blockIdx.x * 64;

    {
        int i  = tid >> 2;
        int jc = (tid & 3) * 16;
        const float4* s = (const float4*)(w1 + i * H + jc);
        float4* d = (float4*)(wS + i * PAD + jc);
        d[0] = s[0]; d[1] = s[1]; d[2] = s[2]; d[3] = s[3];
    }
    {
        int nl = tid >> 2;
        int n  = nb + nl;
        int ic = (tid & 3) * 16;
        if (n < N) {
#pragma unroll
            for (int m = 0; m < 4; ++m) {
                float4 zv = *(const float4*)(z + (size_t)n * H + ic + m * 4);
                zT[(ic + m * 4 + 0) * PAD + nl] = zv.x;
                zT[(ic + m * 4 + 1) * PAD + nl] = zv.y;
                zT[(ic + m * 4 + 2) * PAD + nl] = zv.z;
                zT[(ic + m * 4 + 3) * PAD + nl] = zv.w;
            }
        } else {
#pragma unroll
            for (int m = 0; m < 4; ++m)
#pragma unroll
                for (int q = 0; q < 4; ++q)
                    zT[(ic + m * 4 + q) * PAD + nl] = 0.f;
        }
    }
    __syncthreads();

    int tj = tid & 15, tn = tid >> 4;
    int j0 = tj * 4, n0 = tn * 4;

    float acc[4][4] = {};
#pragma unroll 4
    for (int i = 0; i < H; ++i) {
        float4 a = *(const float4*)(zT + i * PAD + n0);
        float4 b = *(const float4*)(wS + i * PAD + j0);
        float av[4] = {a.x, a.y, a.z, a.w};
        float bv[4] = {b.x, b.y, b.z, b.w};
#pragma unroll
        for (int p = 0; p < 4; ++p)
#pragma unroll
            for (int q = 0; q < 4; ++q)
                acc[p][q] = fmaf(av[p], bv[q], acc[p][q]);
    }
    float4 bb1 = *(const float4*)(b1 + j0);
    float u[4][4];
#pragma unroll
    for (int p = 0; p < 4; ++p) {
        u[p][0] = fmaxf(acc[p][0] + bb1.x, 0.f);
        u[p][1] = fmaxf(acc[p][1] + bb1.y, 0.f);
        u[p][2] = fmaxf(acc[p][2] + bb1.z, 0.f);
        u[p][3] = fmaxf(acc[p][3] + bb1.w, 0.f);
    }
    __syncthreads();

#pragma unroll
    for (int p = 0; p < 4; ++p)
#pragma unroll
        for (int q = 0; q < 4; ++q)
            zT[(j0 + q) * PAD + (n0 + p)] = u[p][q];
    {
        int i  = tid >> 2;
        int jc = (tid & 3) * 16;
        const float4* s = (const float4*)(w2 + i * H + jc);
        float4* d = (float4*)(wS + i * PAD + jc);
        d[0] = s[0]; d[1] = s[1]; d[2] = s[2]; d[3] = s[3];
    }
    __syncthreads();

    float acc2[4][4] = {};
#pragma unroll 4
    for (int i = 0; i < H; ++i) {
        float4 a = *(const float4*)(zT + i * PAD + n0);
        float4 b = *(const float4*)(wS + i * PAD + j0);
        float av[4] = {a.x, a.y, a.z, a.w};
        float bv[4] = {b.x, b.y, b.z, b.w};
#pragma unroll
        for (int p = 0; p < 4; ++p)
#pragma unroll
            for (int q = 0; q < 4; ++q)
                acc2[p][q] = fmaf(av[p], bv[q], acc2[p][q]);
    }
    float4 bb2 = *(const float4*)(b2 + j0);
#pragma unroll
    for (int p = 0; p < 4; ++p) {
        int n = nb + n0 + p;
        if (n < N) {
            float4 r;
            r.x = fmaxf(acc2[p][0] + bb2.x, 0.f);
            r.y = fmaxf(acc2[p][1] + bb2.y, 0.f);
            r.z = fmaxf(acc2[p][2] + bb2.z, 0.f);
            r.w = fmaxf(acc2[p][3] + bb2.w, 0.f);
            *(float4*)(out + (size_t)n * H + j0) = r;
        }
    }
}

// ---------------- mean pool (batch sorted) ----------------
__global__ __launch_bounds__(64) void pool_kernel(
    const float* __restrict__ h, const int* __restrict__ batch,
    float* __restrict__ sums, float* __restrict__ counts, int N)
{
    int lane = threadIdx.x;
    int start = blockIdx.x * 256;
    if (start >= N) return;
    int end = start + 256; if (end > N) end = N;
    int cur = batch[start];
    float acc = 0.f;
    int cnt = 0;
    for (int n = start; n < end; ++n) {
        int g = batch[n];
        if (g != cur) {
            atomicAdd(sums + cur * H + lane, acc);
            if (lane == 0) atomicAdd(counts + cur, (float)cnt);
            acc = 0.f; cnt = 0; cur = g;
        }
        acc += h[(size_t)n * H + lane];
        cnt++;
    }
    atomicAdd(sums + cur * H + lane, acc);
    if (lane == 0) atomicAdd(counts + cur, (float)cnt);
}

__global__ void div_kernel(const float* __restrict__ sums,
                           const float* __restrict__ counts,
                           float* __restrict__ out)
{
    int g = blockIdx.x, j = threadIdx.x;
    out[g * H + j] = sums[g * H + j] / fmaxf(counts[g], 1.0f);
}

extern "C" void kernel_launch(void* const* d_in, const int* in_sizes, int n_in,
                              void* d_out, int out_size, void* d_ws, size_t ws_size,
                              hipStream_t stream)
{
    const float* x     = (const float*)d_in[0];
    const int*   ei    = (const int*)d_in[1];
    const float* eattr = (const float*)d_in[2];
    const int*   batch = (const int*)d_in[3];
    const float* ne_w  = (const float*)d_in[4];
    const float* ne_b  = (const float*)d_in[5];
    const float* ee_w  = (const float*)d_in[6];
    const float* ee_b  = (const float*)d_in[7];
    const float* c1w1  = (const float*)d_in[8];
    const float* c1b1  = (const float*)d_in[9];
    const float* c1w2  = (const float*)d_in[10];
    const float* c1b2  = (const float*)d_in[11];
    const float* c2w1  = (const float*)d_in[12];
    const float* c2b1  = (const float*)d_in[13];
    const float* c2w2  = (const float*)d_in[14];
    const float* c2b2  = (const float*)d_in[15];

    const int N = in_sizes[0];
    const int E = in_sizes[2];
    const int NB = (N + 63) >> BSH;

    // ---- workspace ----
    float* h      = (float*)d_ws;            // N*H
    float* z      = h + (size_t)N * H;       // N*H
    float* sums   = z + (size_t)N * H;       // 64*H
    float* counts = sums + 64 * H;           // 64
    int*   ghist  = (int*)(counts + 64);     // NB
    int*   off    = ghist + NB;              // NB+1
    int*   gcur   = off + NB + 1;            // NB
    uintptr_t p = (uintptr_t)(gcur + NB);
    p = (p + 15) & ~(uintptr_t)15;
    int2*  bed    = (int2*)p;                // E records

    const int eGrid = (E + EPB - 1) / EPB;
    const int mlpGrid = (N + 63) / 64;

    size_t histLds = (size_t)NB * sizeof(int);
    size_t scatLds = (size_t)(2 * EPB + (NB + 1) + NB + 256) * sizeof(int);

    encode_kernel<<<(N * 16 + 255) / 256, 256, 0, stream>>>(x, ne_w, ne_b, h, N);

    // ---- bucket build (once) ----
    hipMemsetAsync(ghist, 0, (size_t)NB * sizeof(int), stream);
    bhist_kernel<<<eGrid, 256, histLds, stream>>>(ei, ghist, E, NB);
    bscan_kernel<<<1, 256, 0, stream>>>(ghist, off, gcur, NB);
    binscatter_kernel<<<eGrid, 256, scatLds, stream>>>(ei, eattr, gcur, bed, E, NB);

    // ---- layer 1 ----
    agg_kernel<<<NB, 1024, 0, stream>>>(h, bed, off, ee_w, ee_b, z, N);
    mlp_kernel<<<mlpGrid, 256, 0, stream>>>(z, c1w1, c1b1, c1w2, c1b2, h, N);

    // ---- layer 2 ----
    agg_kernel<<<NB, 1024, 0, stream>>>(h, bed, off, ee_w, ee_b, z, N);
    mlp_kernel<<<mlpGrid, 256, 0, stream>>>(z, c2w1, c2b1, c2w2, c2b2, h, N);

    // ---- mean pool ----
    hipMemsetAsync(sums, 0, (64 * H + 64) * sizeof(float), stream);
    pool_kernel<<<(N + 255) / 256, 64, 0, stream>>>(h, batch, sums, counts, N);
    div_kernel<<<64, 64, 0, stream>>>(sums, counts, (float*)d_out);
}

// Round 5
// 328.979 us; speedup vs baseline: 3.3094x; 3.2782x over previous
//
#include <hip/hip_runtime.h>

constexpr int H = 64;
constexpr int PAD = 68;     // LDS row stride (floats) for MLP tiles
constexpr int BSH = 6;      // 64 nodes per bucket
constexpr int EPB = 4096;   // edges per binning block
constexpr int EPT = EPB / 256;  // 16 edges per thread

// ---------------- encode: h[n][j] = x[n] * ne_w[j] + ne_b[j] ----------------
__global__ __launch_bounds__(256) void encode_kernel(
    const float* __restrict__ x, const float* __restrict__ nw,
    const float* __restrict__ nb, float* __restrict__ hout, int N)
{
    int idx = blockIdx.x * 256 + threadIdx.x;
    if (idx >= N * 16) return;
    int n = idx >> 4, c = idx & 15;
    float xv = x[n];
    float4 w = ((const float4*)nw)[c];
    float4 b = ((const float4*)nb)[c];
    float4 r;
    r.x = fmaf(xv, w.x, b.x);
    r.y = fmaf(xv, w.y, b.y);
    r.z = fmaf(xv, w.z, b.z);
    r.w = fmaf(xv, w.w, b.w);
    ((float4*)hout)[idx] = r;
}

// ---------------- bucket histogram (LDS-aggregated) ----------------
__global__ __launch_bounds__(256) void bhist_kernel(
    const int* __restrict__ ei, int* __restrict__ ghist, int E, int NB)
{
    extern __shared__ int lh[];               // NB ints
    for (int b = threadIdx.x; b < NB; b += 256) lh[b] = 0;
    __syncthreads();
    int k0 = blockIdx.x * EPB;
#pragma unroll
    for (int i = 0; i < EPT; ++i) {
        int k = k0 + threadIdx.x + i * 256;
        if (k < E) atomicAdd(&lh[ei[E + k] >> BSH], 1);
    }
    __syncthreads();
    for (int b = threadIdx.x; b < NB; b += 256)
        if (lh[b]) atomicAdd(&ghist[b], lh[b]);
}

// ---------------- single-block exclusive scan; also seeds gcur ----------------
__global__ __launch_bounds__(256) void bscan_kernel(
    const int* __restrict__ ghist, int* __restrict__ off,
    int* __restrict__ gcur, int NB)
{
    __shared__ int part[256];
    int t = threadIdx.x;
    const int C = (NB + 255) / 256;
    int loc[16];
    int s = 0;
    for (int j = 0; j < C; ++j) {
        int idx = t * C + j;
        int v = (idx < NB) ? ghist[idx] : 0;
        loc[j] = s; s += v;
    }
    part[t] = s;
    __syncthreads();
    for (int d = 1; d < 256; d <<= 1) {
        int x = (t >= d) ? part[t - d] : 0;
        __syncthreads();
        part[t] += x;
        __syncthreads();
    }
    int base = part[t] - s;
    for (int j = 0; j < C; ++j) {
        int idx = t * C + j;
        if (idx < NB) { int v = base + loc[j]; off[idx] = v; gcur[idx] = v; }
    }
    if (t == 255) off[NB] = part[255];
}

// ---------------- block-aggregated bin scatter ----------------
// Record: (dstLocal<<17 | src, ea) -- src < 2^17, dl < 64.
__global__ __launch_bounds__(256) void binscatter_kernel(
    const int* __restrict__ ei, const float* __restrict__ eattr,
    int* __restrict__ gcur, int2* __restrict__ bed, int E, int NB)
{
    extern __shared__ int smem[];
    int2* stage = (int2*)smem;                // EPB int2
    int*  A     = smem + 2 * EPB;             // NB+1
    int*  B     = A + NB + 1;                 // NB
    int*  part  = B + NB;                     // 256
    int t = threadIdx.x;
    int k0 = blockIdx.x * EPB;

    for (int b = t; b < NB + 1; b += 256) A[b] = 0;
    __syncthreads();

    int dsts[EPT];
#pragma unroll
    for (int i = 0; i < EPT; ++i) {
        int k = k0 + t + i * 256;
        dsts[i] = (k < E) ? ei[E + k] : -1;
        if (dsts[i] >= 0) atomicAdd(&A[dsts[i] >> BSH], 1);
    }
    __syncthreads();

    const int C = (NB + 255) / 256;
    int loc[16];
    int s = 0;
    for (int j = 0; j < C; ++j) {
        int idx = t * C + j;
        int v = (idx < NB) ? A[idx] : 0;
        loc[j] = s; s += v;
    }
    part[t] = s;
    __syncthreads();
    for (int d = 1; d < 256; d <<= 1) {
        int x = (t >= d) ? part[t - d] : 0;
        __syncthreads();
        part[t] += x;
        __syncthreads();
    }
    int base = part[t] - s;
    int tot = part[255];
    for (int j = 0; j < C; ++j) {
        int idx = t * C + j;
        if (idx < NB) { int e = base + loc[j]; A[idx] = e; B[idx] = e; }
    }
    if (t == 255) A[NB] = tot;
    __syncthreads();

#pragma unroll
    for (int i = 0; i < EPT; ++i) {
        if (dsts[i] >= 0) {
            int k = k0 + t + i * 256;
            int b = dsts[i] >> BSH;
            int dl = dsts[i] & 63;
            int slot = atomicAdd(&B[b], 1);
            stage[slot] = make_int2((dl << 17) | ei[k], __float_as_int(eattr[k]));
        }
    }
    __syncthreads();

    for (int b = t; b < NB; b += 256) {
        int c0 = A[b], c1 = B[b];
        if (c1 > c0) B[b] = atomicAdd(&gcur[b], c1 - c0) - c0;
    }
    __syncthreads();

    int s0 = t * EPT;
    int lo = 0, hi = NB;
    while (hi - lo > 1) { int mid = (lo + hi) >> 1; if (A[mid] <= s0) lo = mid; else hi = mid; }
    int b = lo;
#pragma unroll
    for (int i = 0; i < EPT; ++i) {
        int sl = s0 + i;
        if (sl >= tot) break;
        while (sl >= A[b + 1]) ++b;
        bed[B[b] + sl] = stage[sl];
    }
}

// ---------------- per-bucket dl counting-sort -> exact per-node CSR ----------
// One block per bucket: stage records in LDS, sort by dstLocal, write back in
// place; emit nstart/nend per node. Oversize (>4096, unreachable here) bucket
// is left unsorted with full-range nstart/nend -- gather's dl-mask keeps it
// correct.
__global__ __launch_bounds__(256) void dlsort_kernel(
    int2* __restrict__ bed, const int* __restrict__ off,
    int* __restrict__ nstart, int* __restrict__ nend, int N, int NB)
{
    __shared__ int2 stage[4096];
    __shared__ int hist[64], excl[65], cur[64];
    int t = threadIdx.x, b = blockIdx.x;
    int e0 = off[b], e1 = off[b + 1], cnt = e1 - e0;
    if (t < 64) hist[t] = 0;
    __syncthreads();

    if (cnt <= 4096) {
        for (int i = t; i < cnt; i += 256) {
            int2 r = bed[e0 + i];
            stage[i] = r;
            atomicAdd(&hist[(unsigned)r.x >> 17], 1);
        }
        __syncthreads();
        if (t == 0) {
            int s = 0;
#pragma unroll
            for (int i = 0; i < 64; ++i) { excl[i] = s; s += hist[i]; }
            excl[64] = s;
        }
        __syncthreads();
        if (t < 64) {
            cur[t] = excl[t];
            int n = b * 64 + t;
            if (n < N) { nstart[n] = e0 + excl[t]; nend[n] = e0 + excl[t + 1]; }
        }
        __syncthreads();
        for (int i = t; i < cnt; i += 256) {
            int2 r = stage[i];
            int p = atomicAdd(&cur[(unsigned)r.x >> 17], 1);
            bed[e0 + p] = r;
        }
    } else {
        int n = b * 64 + t;
        if (t < 64 && n < N) { nstart[n] = e0; nend[n] = e1; }
    }
}

// ---------------- gather: z[n] = h[n] + sum relu(h[src] + ea*ew + eb) ----
// wave per node, lane = channel, register accumulation, 4-deep ILP
__global__ __launch_bounds__(256) void gather_kernel(
    const float* __restrict__ h, const int2* __restrict__ bed,
    const int* __restrict__ nstart, const int* __restrict__ nend,
    const float* __restrict__ ew, const float* __restrict__ eb,
    float* __restrict__ z, int N)
{
    int lane = threadIdx.x & 63;
    int wid  = threadIdx.x >> 6;
    int n = blockIdx.x * 4 + wid;
    if (n >= N) return;
    float wj = ew[lane], bj = eb[lane];
    int e  = nstart[n];
    int e1 = nend[n];
    unsigned mydl = (unsigned)(n & 63);
    float acc = h[(size_t)n * H + lane];    // self term (eps = 0)

    for (; e + 4 <= e1; e += 4) {
        int2 r0 = bed[e];
        int2 r1 = bed[e + 1];
        int2 r2 = bed[e + 2];
        int2 r3 = bed[e + 3];
        float h0 = h[(size_t)(r0.x & 0x1FFFF) * H + lane];
        float h1 = h[(size_t)(r1.x & 0x1FFFF) * H + lane];
        float h2 = h[(size_t)(r2.x & 0x1FFFF) * H + lane];
        float h3 = h[(size_t)(r3.x & 0x1FFFF) * H + lane];
        float m0 = fmaxf(fmaf(__int_as_float(r0.y), wj, bj) + h0, 0.f);
        float m1 = fmaxf(fmaf(__int_as_float(r1.y), wj, bj) + h1, 0.f);
        float m2 = fmaxf(fmaf(__int_as_float(r2.y), wj, bj) + h2, 0.f);
        float m3 = fmaxf(fmaf(__int_as_float(r3.y), wj, bj) + h3, 0.f);
        acc += (((unsigned)r0.x >> 17) == mydl ? m0 : 0.f)
             + (((unsigned)r1.x >> 17) == mydl ? m1 : 0.f)
             + (((unsigned)r2.x >> 17) == mydl ? m2 : 0.f)
             + (((unsigned)r3.x >> 17) == mydl ? m3 : 0.f);
    }
    for (; e < e1; ++e) {
        int2 r = bed[e];
        float m = fmaxf(fmaf(__int_as_float(r.y), wj, bj)
                        + h[(size_t)(r.x & 0x1FFFF) * H + lane], 0.f);
        acc += (((unsigned)r.x >> 17) == mydl ? m : 0.f);
    }
    z[(size_t)n * H + lane] = acc;
}

// ---------------- per 64-node tile MLP ----------------
__global__ __launch_bounds__(256) void mlp_kernel(
    const float* __restrict__ z, const float* __restrict__ w1,
    const float* __restrict__ b1, const float* __restrict__ w2,
    const float* __restrict__ b2, float* __restrict__ out, int N)
{
    __shared__ float zT[H * PAD];
    __shared__ float wS[H * PAD];
    int tid = threadIdx.x;
    int nb = blockIdx.x * 64;

    {
        int i  = tid >> 2;
        int jc = (tid & 3) * 16;
        const float4* s = (const float4*)(w1 + i * H + jc);
        float4* d = (float4*)(wS + i * PAD + jc);
        d[0] = s[0]; d[1] = s[1]; d[2] = s[2]; d[3] = s[3];
    }
    {
        int nl = tid >> 2;
        int n  = nb + nl;
        int ic = (tid & 3) * 16;
        if (n < N) {
#pragma unroll
            for (int m = 0; m < 4; ++m) {
                float4 zv = *(const float4*)(z + (size_t)n * H + ic + m * 4);
                zT[(ic + m * 4 + 0) * PAD + nl] = zv.x;
                zT[(ic + m * 4 + 1) * PAD + nl] = zv.y;
                zT[(ic + m * 4 + 2) * PAD + nl] = zv.z;
                zT[(ic + m * 4 + 3) * PAD + nl] = zv.w;
            }
        } else {
#pragma unroll
            for (int m = 0; m < 4; ++m)
#pragma unroll
                for (int q = 0; q < 4; ++q)
                    zT[(ic + m * 4 + q) * PAD + nl] = 0.f;
        }
    }
    __syncthreads();

    int tj = tid & 15, tn = tid >> 4;
    int j0 = tj * 4, n0 = tn * 4;

    float acc[4][4] = {};
#pragma unroll 4
    for (int i = 0; i < H; ++i) {
        float4 a = *(const float4*)(zT + i * PAD + n0);
        float4 b = *(const float4*)(wS + i * PAD + j0);
        float av[4] = {a.x, a.y, a.z, a.w};
        float bv[4] = {b.x, b.y, b.z, b.w};
#pragma unroll
        for (int p = 0; p < 4; ++p)
#pragma unroll
            for (int q = 0; q < 4; ++q)
                acc[p][q] = fmaf(av[p], bv[q], acc[p][q]);
    }
    float4 bb1 = *(const float4*)(b1 + j0);
    float u[4][4];
#pragma unroll
    for (int p = 0; p < 4; ++p) {
        u[p][0] = fmaxf(acc[p][0] + bb1.x, 0.f);
        u[p][1] = fmaxf(acc[p][1] + bb1.y, 0.f);
        u[p][2] = fmaxf(acc[p][2] + bb1.z, 0.f);
        u[p][3] = fmaxf(acc[p][3] + bb1.w, 0.f);
    }
    __syncthreads();

#pragma unroll
    for (int p = 0; p < 4; ++p)
#pragma unroll
        for (int q = 0; q < 4; ++q)
            zT[(j0 + q) * PAD + (n0 + p)] = u[p][q];
    {
        int i  = tid >> 2;
        int jc = (tid & 3) * 16;
        const float4* s = (const float4*)(w2 + i * H + jc);
        float4* d = (float4*)(wS + i * PAD + jc);
        d[0] = s[0]; d[1] = s[1]; d[2] = s[2]; d[3] = s[3];
    }
    __syncthreads();

    float acc2[4][4] = {};
#pragma unroll 4
    for (int i = 0; i < H; ++i) {
        float4 a = *(const float4*)(zT + i * PAD + n0);
        float4 b = *(const float4*)(wS + i * PAD + j0);
        float av[4] = {a.x, a.y, a.z, a.w};
        float bv[4] = {b.x, b.y, b.z, b.w};
#pragma unroll
        for (int p = 0; p < 4; ++p)
#pragma unroll
            for (int q = 0; q < 4; ++q)
                acc2[p][q] = fmaf(av[p], bv[q], acc2[p][q]);
    }
    float4 bb2 = *(const float4*)(b2 + j0);
#pragma unroll
    for (int p = 0; p < 4; ++p) {
        int n = nb + n0 + p;
        if (n < N) {
            float4 r;
            r.x = fmaxf(acc2[p][0] + bb2.x, 0.f);
            r.y = fmaxf(acc2[p][1] + bb2.y, 0.f);
            r.z = fmaxf(acc2[p][2] + bb2.z, 0.f);
            r.w = fmaxf(acc2[p][3] + bb2.w, 0.f);
            *(float4*)(out + (size_t)n * H + j0) = r;
        }
    }
}

// ---------------- mean pool (batch sorted) ----------------
__global__ __launch_bounds__(64) void pool_kernel(
    const float* __restrict__ h, const int* __restrict__ batch,
    float* __restrict__ sums, float* __restrict__ counts, int N)
{
    int lane = threadIdx.x;
    int start = blockIdx.x * 256;
    if (start >= N) return;
    int end = start + 256; if (end > N) end = N;
    int cur = batch[start];
    float acc = 0.f;
    int cnt = 0;
    for (int n = start; n < end; ++n) {
        int g = batch[n];
        if (g != cur) {
            atomicAdd(sums + cur * H + lane, acc);
            if (lane == 0) atomicAdd(counts + cur, (float)cnt);
            acc = 0.f; cnt = 0; cur = g;
        }
        acc += h[(size_t)n * H + lane];
        cnt++;
    }
    atomicAdd(sums + cur * H + lane, acc);
    if (lane == 0) atomicAdd(counts + cur, (float)cnt);
}

__global__ void div_kernel(const float* __restrict__ sums,
                           const float* __restrict__ counts,
                           float* __restrict__ out)
{
    int g = blockIdx.x, j = threadIdx.x;
    out[g * H + j] = sums[g * H + j] / fmaxf(counts[g], 1.0f);
}

extern "C" void kernel_launch(void* const* d_in, const int* in_sizes, int n_in,
                              void* d_out, int out_size, void* d_ws, size_t ws_size,
                              hipStream_t stream)
{
    const float* x     = (const float*)d_in[0];
    const int*   ei    = (const int*)d_in[1];
    const float* eattr = (const float*)d_in[2];
    const int*   batch = (const int*)d_in[3];
    const float* ne_w  = (const float*)d_in[4];
    const float* ne_b  = (const float*)d_in[5];
    const float* ee_w  = (const float*)d_in[6];
    const float* ee_b  = (const float*)d_in[7];
    const float* c1w1  = (const float*)d_in[8];
    const float* c1b1  = (const float*)d_in[9];
    const float* c1w2  = (const float*)d_in[10];
    const float* c1b2  = (const float*)d_in[11];
    const float* c2w1  = (const float*)d_in[12];
    const float* c2b1  = (const float*)d_in[13];
    const float* c2w2  = (const float*)d_in[14];
    const float* c2b2  = (const float*)d_in[15];

    const int N = in_sizes[0];
    const int E = in_sizes[2];
    const int NB = (N + 63) >> BSH;

    // ---- workspace ----
    float* h      = (float*)d_ws;            // N*H
    float* z      = h + (size_t)N * H;       // N*H
    float* sums   = z + (size_t)N * H;       // 64*H
    float* counts = sums + 64 * H;           // 64
    int*   ghist  = (int*)(counts + 64);     // NB
    int*   off    = ghist + NB;              // NB+1
    int*   gcur   = off + NB + 1;            // NB
    int*   nstart = gcur + NB;               // N
    int*   nend   = nstart + N;              // N
    uintptr_t p = (uintptr_t)(nend + N);
    p = (p + 15) & ~(uintptr_t)15;
    int2*  bed    = (int2*)p;                // E records

    const int eGrid = (E + EPB - 1) / EPB;
    const int mlpGrid = (N + 63) / 64;

    size_t histLds = (size_t)NB * sizeof(int);
    size_t scatLds = (size_t)(2 * EPB + (NB + 1) + NB + 256) * sizeof(int);

    encode_kernel<<<(N * 16 + 255) / 256, 256, 0, stream>>>(x, ne_w, ne_b, h, N);

    // ---- bucket build + exact CSR (once, reused by both layers) ----
    hipMemsetAsync(ghist, 0, (size_t)NB * sizeof(int), stream);
    bhist_kernel<<<eGrid, 256, histLds, stream>>>(ei, ghist, E, NB);
    bscan_kernel<<<1, 256, 0, stream>>>(ghist, off, gcur, NB);
    binscatter_kernel<<<eGrid, 256, scatLds, stream>>>(ei, eattr, gcur, bed, E, NB);
    dlsort_kernel<<<NB, 256, 0, stream>>>(bed, off, nstart, nend, N, NB);

    const int gatherGrid = (N + 3) / 4;

    // ---- layer 1 ----
    gather_kernel<<<gatherGrid, 256, 0, stream>>>(h, bed, nstart, nend, ee_w, ee_b, z, N);
    mlp_kernel<<<mlpGrid, 256, 0, stream>>>(z, c1w1, c1b1, c1w2, c1b2, h, N);

    // ---- layer 2 ----
    gather_kernel<<<gatherGrid, 256, 0, stream>>>(h, bed, nstart, nend, ee_w, ee_b, z, N);
    mlp_kernel<<<mlpGrid, 256, 0, stream>>>(z, c2w1, c2b1, c2w2, c2b2, h, N);

    // ---- mean pool ----
    hipMemsetAsync(sums, 0, (64 * H + 64) * sizeof(float), stream);
    pool_kernel<<<(N + 255) / 256, 64, 0, stream>>>(h, batch, sums, counts, N);
    div_kernel<<<64, 64, 0, stream>>>(sums, counts, (float*)d_out);
}

// Round 6
// 288.028 us; speedup vs baseline: 3.7800x; 1.1422x over previous
//
#include <hip/hip_runtime.h>

constexpr int H = 64;
constexpr int PAD = 68;     // LDS row stride (floats) for MLP tiles
constexpr int BSH = 6;      // 64 nodes per bucket
constexpr int EPB = 4096;   // edges per binning block
constexpr int EPT = EPB / 256;  // 16 edges per thread

// ---------------- encode: h[n][j] = x[n] * ne_w[j] + ne_b[j] ----------------
__global__ __launch_bounds__(256) void encode_kernel(
    const float* __restrict__ x, const float* __restrict__ nw,
    const float* __restrict__ nb, float* __restrict__ hout, int N)
{
    int idx = blockIdx.x * 256 + threadIdx.x;
    if (idx >= N * 16) return;
    int n = idx >> 4, c = idx & 15;
    float xv = x[n];
    float4 w = ((const float4*)nw)[c];
    float4 b = ((const float4*)nb)[c];
    float4 r;
    r.x = fmaf(xv, w.x, b.x);
    r.y = fmaf(xv, w.y, b.y);
    r.z = fmaf(xv, w.z, b.z);
    r.w = fmaf(xv, w.w, b.w);
    ((float4*)hout)[idx] = r;
}

// ---------------- bucket histogram (LDS-aggregated) ----------------
__global__ __launch_bounds__(256) void bhist_kernel(
    const int* __restrict__ ei, int* __restrict__ ghist, int E, int NB)
{
    extern __shared__ int lh[];               // NB ints
    for (int b = threadIdx.x; b < NB; b += 256) lh[b] = 0;
    __syncthreads();
    int k0 = blockIdx.x * EPB;
#pragma unroll
    for (int i = 0; i < EPT; ++i) {
        int k = k0 + threadIdx.x + i * 256;
        if (k < E) atomicAdd(&lh[ei[E + k] >> BSH], 1);
    }
    __syncthreads();
    for (int b = threadIdx.x; b < NB; b += 256)
        if (lh[b]) atomicAdd(&ghist[b], lh[b]);
}

// ---------------- single-block exclusive scan; also seeds gcur ----------------
__global__ __launch_bounds__(256) void bscan_kernel(
    const int* __restrict__ ghist, int* __restrict__ off,
    int* __restrict__ gcur, int NB)
{
    __shared__ int part[256];
    int t = threadIdx.x;
    const int C = (NB + 255) / 256;
    int loc[16];
    int s = 0;
    for (int j = 0; j < C; ++j) {
        int idx = t * C + j;
        int v = (idx < NB) ? ghist[idx] : 0;
        loc[j] = s; s += v;
    }
    part[t] = s;
    __syncthreads();
    for (int d = 1; d < 256; d <<= 1) {
        int x = (t >= d) ? part[t - d] : 0;
        __syncthreads();
        part[t] += x;
        __syncthreads();
    }
    int base = part[t] - s;
    for (int j = 0; j < C; ++j) {
        int idx = t * C + j;
        if (idx < NB) { int v = base + loc[j]; off[idx] = v; gcur[idx] = v; }
    }
    if (t == 255) off[NB] = part[255];
}

// ---------------- block-aggregated bin scatter ----------------
// Record: (dstLocal<<17 | src, ea) -- src < 2^17, dl < 64.
__global__ __launch_bounds__(256) void binscatter_kernel(
    const int* __restrict__ ei, const float* __restrict__ eattr,
    int* __restrict__ gcur, int2* __restrict__ bed, int E, int NB)
{
    extern __shared__ int smem[];
    int2* stage = (int2*)smem;                // EPB int2
    int*  A     = smem + 2 * EPB;             // NB+1
    int*  B     = A + NB + 1;                 // NB
    int*  part  = B + NB;                     // 256
    int t = threadIdx.x;
    int k0 = blockIdx.x * EPB;

    for (int b = t; b < NB + 1; b += 256) A[b] = 0;
    __syncthreads();

    int dsts[EPT];
#pragma unroll
    for (int i = 0; i < EPT; ++i) {
        int k = k0 + t + i * 256;
        dsts[i] = (k < E) ? ei[E + k] : -1;
        if (dsts[i] >= 0) atomicAdd(&A[dsts[i] >> BSH], 1);
    }
    __syncthreads();

    const int C = (NB + 255) / 256;
    int loc[16];
    int s = 0;
    for (int j = 0; j < C; ++j) {
        int idx = t * C + j;
        int v = (idx < NB) ? A[idx] : 0;
        loc[j] = s; s += v;
    }
    part[t] = s;
    __syncthreads();
    for (int d = 1; d < 256; d <<= 1) {
        int x = (t >= d) ? part[t - d] : 0;
        __syncthreads();
        part[t] += x;
        __syncthreads();
    }
    int base = part[t] - s;
    int tot = part[255];
    for (int j = 0; j < C; ++j) {
        int idx = t * C + j;
        if (idx < NB) { int e = base + loc[j]; A[idx] = e; B[idx] = e; }
    }
    if (t == 255) A[NB] = tot;
    __syncthreads();

#pragma unroll
    for (int i = 0; i < EPT; ++i) {
        if (dsts[i] >= 0) {
            int k = k0 + t + i * 256;
            int b = dsts[i] >> BSH;
            int dl = dsts[i] & 63;
            int slot = atomicAdd(&B[b], 1);
            stage[slot] = make_int2((dl << 17) | ei[k], __float_as_int(eattr[k]));
        }
    }
    __syncthreads();

    for (int b = t; b < NB; b += 256) {
        int c0 = A[b], c1 = B[b];
        if (c1 > c0) B[b] = atomicAdd(&gcur[b], c1 - c0) - c0;
    }
    __syncthreads();

    int s0 = t * EPT;
    int lo = 0, hi = NB;
    while (hi - lo > 1) { int mid = (lo + hi) >> 1; if (A[mid] <= s0) lo = mid; else hi = mid; }
    int b = lo;
#pragma unroll
    for (int i = 0; i < EPT; ++i) {
        int sl = s0 + i;
        if (sl >= tot) break;
        while (sl >= A[b + 1]) ++b;
        bed[B[b] + sl] = stage[sl];
    }
}

// ---------------- per-bucket dl counting-sort -> exact per-node CSR ----------
__global__ __launch_bounds__(256) void dlsort_kernel(
    int2* __restrict__ bed, const int* __restrict__ off,
    int* __restrict__ nstart, int* __restrict__ nend, int N, int NB)
{
    __shared__ int2 stage[4096];
    __shared__ int hist[64], excl[65], cur[64];
    int t = threadIdx.x, b = blockIdx.x;
    int e0 = off[b], e1 = off[b + 1], cnt = e1 - e0;
    if (t < 64) hist[t] = 0;
    __syncthreads();

    if (cnt <= 4096) {
        for (int i = t; i < cnt; i += 256) {
            int2 r = bed[e0 + i];
            stage[i] = r;
            atomicAdd(&hist[(unsigned)r.x >> 17], 1);
        }
        __syncthreads();
        if (t == 0) {
            int s = 0;
#pragma unroll
            for (int i = 0; i < 64; ++i) { excl[i] = s; s += hist[i]; }
            excl[64] = s;
        }
        __syncthreads();
        if (t < 64) {
            cur[t] = excl[t];
            int n = b * 64 + t;
            if (n < N) { nstart[n] = e0 + excl[t]; nend[n] = e0 + excl[t + 1]; }
        }
        __syncthreads();
        for (int i = t; i < cnt; i += 256) {
            int2 r = stage[i];
            int p = atomicAdd(&cur[(unsigned)r.x >> 17], 1);
            bed[e0 + p] = r;
        }
    } else {
        int n = b * 64 + t;
        if (t < 64 && n < N) { nstart[n] = e0; nend[n] = e1; }
    }
}

// ---------------- gather: z[n] = h[n] + sum relu(h[src] + ea*ew + eb) ----
// wave per node, lane = channel, register accumulation, 4-deep ILP
__global__ __launch_bounds__(256) void gather_kernel(
    const float* __restrict__ h, const int2* __restrict__ bed,
    const int* __restrict__ nstart, const int* __restrict__ nend,
    const float* __restrict__ ew, const float* __restrict__ eb,
    float* __restrict__ z, int N)
{
    int lane = threadIdx.x & 63;
    int wid  = threadIdx.x >> 6;
    int n = blockIdx.x * 4 + wid;
    if (n >= N) return;
    float wj = ew[lane], bj = eb[lane];
    int e  = nstart[n];
    int e1 = nend[n];
    unsigned mydl = (unsigned)(n & 63);
    float acc = h[(size_t)n * H + lane];    // self term (eps = 0)

    for (; e + 4 <= e1; e += 4) {
        int2 r0 = bed[e];
        int2 r1 = bed[e + 1];
        int2 r2 = bed[e + 2];
        int2 r3 = bed[e + 3];
        float h0 = h[(size_t)(r0.x & 0x1FFFF) * H + lane];
        float h1 = h[(size_t)(r1.x & 0x1FFFF) * H + lane];
        float h2 = h[(size_t)(r2.x & 0x1FFFF) * H + lane];
        float h3 = h[(size_t)(r3.x & 0x1FFFF) * H + lane];
        float m0 = fmaxf(fmaf(__int_as_float(r0.y), wj, bj) + h0, 0.f);
        float m1 = fmaxf(fmaf(__int_as_float(r1.y), wj, bj) + h1, 0.f);
        float m2 = fmaxf(fmaf(__int_as_float(r2.y), wj, bj) + h2, 0.f);
        float m3 = fmaxf(fmaf(__int_as_float(r3.y), wj, bj) + h3, 0.f);
        acc += (((unsigned)r0.x >> 17) == mydl ? m0 : 0.f)
             + (((unsigned)r1.x >> 17) == mydl ? m1 : 0.f)
             + (((unsigned)r2.x >> 17) == mydl ? m2 : 0.f)
             + (((unsigned)r3.x >> 17) == mydl ? m3 : 0.f);
    }
    for (; e < e1; ++e) {
        int2 r = bed[e];
        float m = fmaxf(fmaf(__int_as_float(r.y), wj, bj)
                        + h[(size_t)(r.x & 0x1FFFF) * H + lane], 0.f);
        acc += (((unsigned)r.x >> 17) == mydl ? m : 0.f);
    }
    z[(size_t)n * H + lane] = acc;
}

// ---------------- per 64-node tile MLP ----------------
__global__ __launch_bounds__(256) void mlp_kernel(
    const float* __restrict__ z, const float* __restrict__ w1,
    const float* __restrict__ b1, const float* __restrict__ w2,
    const float* __restrict__ b2, float* __restrict__ out, int N)
{
    __shared__ float zT[H * PAD];
    __shared__ float wS[H * PAD];
    int tid = threadIdx.x;
    int nb = blockIdx.x * 64;

    {
        int i  = tid >> 2;
        int jc = (tid & 3) * 16;
        const float4* s = (const float4*)(w1 + i * H + jc);
        float4* d = (float4*)(wS + i * PAD + jc);
        d[0] = s[0]; d[1] = s[1]; d[2] = s[2]; d[3] = s[3];
    }
    {
        int nl = tid >> 2;
        int n  = nb + nl;
        int ic = (tid & 3) * 16;
        if (n < N) {
#pragma unroll
            for (int m = 0; m < 4; ++m) {
                float4 zv = *(const float4*)(z + (size_t)n * H + ic + m * 4);
                zT[(ic + m * 4 + 0) * PAD + nl] = zv.x;
                zT[(ic + m * 4 + 1) * PAD + nl] = zv.y;
                zT[(ic + m * 4 + 2) * PAD + nl] = zv.z;
                zT[(ic + m * 4 + 3) * PAD + nl] = zv.w;
            }
        } else {
#pragma unroll
            for (int m = 0; m < 4; ++m)
#pragma unroll
                for (int q = 0; q < 4; ++q)
                    zT[(ic + m * 4 + q) * PAD + nl] = 0.f;
        }
    }
    __syncthreads();

    int tj = tid & 15, tn = tid >> 4;
    int j0 = tj * 4, n0 = tn * 4;

    float acc[4][4] = {};
#pragma unroll 4
    for (int i = 0; i < H; ++i) {
        float4 a = *(const float4*)(zT + i * PAD + n0);
        float4 b = *(const float4*)(wS + i * PAD + j0);
        float av[4] = {a.x, a.y, a.z, a.w};
        float bv[4] = {b.x, b.y, b.z, b.w};
#pragma unroll
        for (int p = 0; p < 4; ++p)
#pragma unroll
            for (int q = 0; q < 4; ++q)
                acc[p][q] = fmaf(av[p], bv[q], acc[p][q]);
    }
    float4 bb1 = *(const float4*)(b1 + j0);
    float u[4][4];
#pragma unroll
    for (int p = 0; p < 4; ++p) {
        u[p][0] = fmaxf(acc[p][0] + bb1.x, 0.f);
        u[p][1] = fmaxf(acc[p][1] + bb1.y, 0.f);
        u[p][2] = fmaxf(acc[p][2] + bb1.z, 0.f);
        u[p][3] = fmaxf(acc[p][3] + bb1.w, 0.f);
    }
    __syncthreads();

#pragma unroll
    for (int p = 0; p < 4; ++p)
#pragma unroll
        for (int q = 0; q < 4; ++q)
            zT[(j0 + q) * PAD + (n0 + p)] = u[p][q];
    {
        int i  = tid >> 2;
        int jc = (tid & 3) * 16;
        const float4* s = (const float4*)(w2 + i * H + jc);
        float4* d = (float4*)(wS + i * PAD + jc);
        d[0] = s[0]; d[1] = s[1]; d[2] = s[2]; d[3] = s[3];
    }
    __syncthreads();

    float acc2[4][4] = {};
#pragma unroll 4
    for (int i = 0; i < H; ++i) {
        float4 a = *(const float4*)(zT + i * PAD + n0);
        float4 b = *(const float4*)(wS + i * PAD + j0);
        float av[4] = {a.x, a.y, a.z, a.w};
        float bv[4] = {b.x, b.y, b.z, b.w};
#pragma unroll
        for (int p = 0; p < 4; ++p)
#pragma unroll
            for (int q = 0; q < 4; ++q)
                acc2[p][q] = fmaf(av[p], bv[q], acc2[p][q]);
    }
    float4 bb2 = *(const float4*)(b2 + j0);
#pragma unroll
    for (int p = 0; p < 4; ++p) {
        int n = nb + n0 + p;
        if (n < N) {
            float4 r;
            r.x = fmaxf(acc2[p][0] + bb2.x, 0.f);
            r.y = fmaxf(acc2[p][1] + bb2.y, 0.f);
            r.z = fmaxf(acc2[p][2] + bb2.z, 0.f);
            r.w = fmaxf(acc2[p][3] + bb2.w, 0.f);
            *(float4*)(out + (size_t)n * H + j0) = r;
        }
    }
}

// ---------------- mean pool v2 (batch sorted): 4 waves/block, 64 nodes/wave --
// 256-thread blocks; wave w owns nodes [blk*256 + w*64, +64), lane = channel.
// ~1563 waves total (6/CU) hides the serial-chain latency that capped v1.
__global__ __launch_bounds__(256) void pool_kernel(
    const float* __restrict__ h, const int* __restrict__ batch,
    float* __restrict__ sums, float* __restrict__ counts, int N)
{
    int lane = threadIdx.x & 63;
    int wid  = threadIdx.x >> 6;
    int start = blockIdx.x * 256 + wid * 64;
    if (start >= N) return;
    int end = start + 64; if (end > N) end = N;
    int cur = batch[start];
    float acc = 0.f;
    int cnt = 0;
    for (int n = start; n < end; ++n) {
        int g = batch[n];
        if (g != cur) {
            atomicAdd(sums + cur * H + lane, acc);
            if (lane == 0) atomicAdd(counts + cur, (float)cnt);
            acc = 0.f; cnt = 0; cur = g;
        }
        acc += h[(size_t)n * H + lane];
        cnt++;
    }
    atomicAdd(sums + cur * H + lane, acc);
    if (lane == 0) atomicAdd(counts + cur, (float)cnt);
}

__global__ void div_kernel(const float* __restrict__ sums,
                           const float* __restrict__ counts,
                           float* __restrict__ out)
{
    int g = blockIdx.x, j = threadIdx.x;
    out[g * H + j] = sums[g * H + j] / fmaxf(counts[g], 1.0f);
}

extern "C" void kernel_launch(void* const* d_in, const int* in_sizes, int n_in,
                              void* d_out, int out_size, void* d_ws, size_t ws_size,
                              hipStream_t stream)
{
    const float* x     = (const float*)d_in[0];
    const int*   ei    = (const int*)d_in[1];
    const float* eattr = (const float*)d_in[2];
    const int*   batch = (const int*)d_in[3];
    const float* ne_w  = (const float*)d_in[4];
    const float* ne_b  = (const float*)d_in[5];
    const float* ee_w  = (const float*)d_in[6];
    const float* ee_b  = (const float*)d_in[7];
    const float* c1w1  = (const float*)d_in[8];
    const float* c1b1  = (const float*)d_in[9];
    const float* c1w2  = (const float*)d_in[10];
    const float* c1b2  = (const float*)d_in[11];
    const float* c2w1  = (const float*)d_in[12];
    const float* c2b1  = (const float*)d_in[13];
    const float* c2w2  = (const float*)d_in[14];
    const float* c2b2  = (const float*)d_in[15];

    const int N = in_sizes[0];
    const int E = in_sizes[2];
    const int NB = (N + 63) >> BSH;

    // ---- workspace ----
    float* h      = (float*)d_ws;            // N*H
    float* z      = h + (size_t)N * H;       // N*H
    float* sums   = z + (size_t)N * H;       // 64*H
    float* counts = sums + 64 * H;           // 64
    int*   ghist  = (int*)(counts + 64);     // NB
    int*   off    = ghist + NB;              // NB+1
    int*   gcur   = off + NB + 1;            // NB
    int*   nstart = gcur + NB;               // N
    int*   nend   = nstart + N;              // N
    uintptr_t p = (uintptr_t)(nend + N);
    p = (p + 15) & ~(uintptr_t)15;
    int2*  bed    = (int2*)p;                // E records

    const int eGrid = (E + EPB - 1) / EPB;
    const int mlpGrid = (N + 63) / 64;

    size_t histLds = (size_t)NB * sizeof(int);
    size_t scatLds = (size_t)(2 * EPB + (NB + 1) + NB + 256) * sizeof(int);

    encode_kernel<<<(N * 16 + 255) / 256, 256, 0, stream>>>(x, ne_w, ne_b, h, N);

    // ---- bucket build + exact CSR (once, reused by both layers) ----
    hipMemsetAsync(ghist, 0, (size_t)NB * sizeof(int), stream);
    bhist_kernel<<<eGrid, 256, histLds, stream>>>(ei, ghist, E, NB);
    bscan_kernel<<<1, 256, 0, stream>>>(ghist, off, gcur, NB);
    binscatter_kernel<<<eGrid, 256, scatLds, stream>>>(ei, eattr, gcur, bed, E, NB);
    dlsort_kernel<<<NB, 256, 0, stream>>>(bed, off, nstart, nend, N, NB);

    const int gatherGrid = (N + 3) / 4;

    // ---- layer 1 ----
    gather_kernel<<<gatherGrid, 256, 0, stream>>>(h, bed, nstart, nend, ee_w, ee_b, z, N);
    mlp_kernel<<<mlpGrid, 256, 0, stream>>>(z, c1w1, c1b1, c1w2, c1b2, h, N);

    // ---- layer 2 ----
    gather_kernel<<<gatherGrid, 256, 0, stream>>>(h, bed, nstart, nend, ee_w, ee_b, z, N);
    mlp_kernel<<<mlpGrid, 256, 0, stream>>>(z, c2w1, c2b1, c2w2, c2b2, h, N);

    // ---- mean pool ----
    hipMemsetAsync(sums, 0, (64 * H + 64) * sizeof(float), stream);
    pool_kernel<<<(N + 255) / 256, 256, 0, stream>>>(h, batch, sums, counts, N);
    div_kernel<<<64, 64, 0, stream>>>(sums, counts, (float*)d_out);
}

// Round 7
// 242.958 us; speedup vs baseline: 4.4811x; 1.1855x over previous
//
#include <hip/hip_runtime.h>
#include <hip/hip_fp16.h>

constexpr int H = 64;
constexpr int PAD = 68;     // LDS row stride (floats) for MLP tiles
constexpr int BSH = 6;      // 64 nodes per bucket
constexpr int EPB = 4096;   // edges per binning block
constexpr int EPT = EPB / 256;  // 16 edges per thread

__device__ inline unsigned pack2(float a, float b) {
    __half2 hh = __floats2half2_rn(a, b);
    return *(unsigned*)&hh;
}

// ---------------- encode: h16[n][j] = x[n] * ne_w[j] + ne_b[j] ----------------
__global__ __launch_bounds__(256) void encode_kernel(
    const float* __restrict__ x, const float* __restrict__ nw,
    const float* __restrict__ nb, __half* __restrict__ hout, int N)
{
    int idx = blockIdx.x * 256 + threadIdx.x;        // over N*16 groups of 4ch
    if (idx >= N * 16) return;
    int n = idx >> 4, c = idx & 15;
    float xv = x[n];
    float4 w = ((const float4*)nw)[c];
    float4 b = ((const float4*)nb)[c];
    uint2 r;
    r.x = pack2(fmaf(xv, w.x, b.x), fmaf(xv, w.y, b.y));
    r.y = pack2(fmaf(xv, w.z, b.z), fmaf(xv, w.w, b.w));
    ((uint2*)hout)[idx] = r;
}

// ---------------- bucket histogram (LDS-aggregated) ----------------
__global__ __launch_bounds__(256) void bhist_kernel(
    const int* __restrict__ ei, int* __restrict__ ghist, int E, int NB)
{
    extern __shared__ int lh[];               // NB ints
    for (int b = threadIdx.x; b < NB; b += 256) lh[b] = 0;
    __syncthreads();
    int k0 = blockIdx.x * EPB;
#pragma unroll
    for (int i = 0; i < EPT; ++i) {
        int k = k0 + threadIdx.x + i * 256;
        if (k < E) atomicAdd(&lh[ei[E + k] >> BSH], 1);
    }
    __syncthreads();
    for (int b = threadIdx.x; b < NB; b += 256)
        if (lh[b]) atomicAdd(&ghist[b], lh[b]);
}

// ---------------- single-block exclusive scan; also seeds gcur ----------------
__global__ __launch_bounds__(256) void bscan_kernel(
    const int* __restrict__ ghist, int* __restrict__ off,
    int* __restrict__ gcur, int NB)
{
    __shared__ int part[256];
    int t = threadIdx.x;
    const int C = (NB + 255) / 256;
    int loc[16];
    int s = 0;
    for (int j = 0; j < C; ++j) {
        int idx = t * C + j;
        int v = (idx < NB) ? ghist[idx] : 0;
        loc[j] = s; s += v;
    }
    part[t] = s;
    __syncthreads();
    for (int d = 1; d < 256; d <<= 1) {
        int x = (t >= d) ? part[t - d] : 0;
        __syncthreads();
        part[t] += x;
        __syncthreads();
    }
    int base = part[t] - s;
    for (int j = 0; j < C; ++j) {
        int idx = t * C + j;
        if (idx < NB) { int v = base + loc[j]; off[idx] = v; gcur[idx] = v; }
    }
    if (t == 255) off[NB] = part[255];
}

// ---------------- block-aggregated bin scatter ----------------
// Record: (dstLocal<<17 | src, ea) -- src < 2^17, dl < 64.
__global__ __launch_bounds__(256) void binscatter_kernel(
    const int* __restrict__ ei, const float* __restrict__ eattr,
    int* __restrict__ gcur, int2* __restrict__ bed, int E, int NB)
{
    extern __shared__ int smem[];
    int2* stage = (int2*)smem;                // EPB int2
    int*  A     = smem + 2 * EPB;             // NB+1
    int*  B     = A + NB + 1;                 // NB
    int*  part  = B + NB;                     // 256
    int t = threadIdx.x;
    int k0 = blockIdx.x * EPB;

    for (int b = t; b < NB + 1; b += 256) A[b] = 0;
    __syncthreads();

    int dsts[EPT];
#pragma unroll
    for (int i = 0; i < EPT; ++i) {
        int k = k0 + t + i * 256;
        dsts[i] = (k < E) ? ei[E + k] : -1;
        if (dsts[i] >= 0) atomicAdd(&A[dsts[i] >> BSH], 1);
    }
    __syncthreads();

    const int C = (NB + 255) / 256;
    int loc[16];
    int s = 0;
    for (int j = 0; j < C; ++j) {
        int idx = t * C + j;
        int v = (idx < NB) ? A[idx] : 0;
        loc[j] = s; s += v;
    }
    part[t] = s;
    __syncthreads();
    for (int d = 1; d < 256; d <<= 1) {
        int x = (t >= d) ? part[t - d] : 0;
        __syncthreads();
        part[t] += x;
        __syncthreads();
    }
    int base = part[t] - s;
    int tot = part[255];
    for (int j = 0; j < C; ++j) {
        int idx = t * C + j;
        if (idx < NB) { int e = base + loc[j]; A[idx] = e; B[idx] = e; }
    }
    if (t == 255) A[NB] = tot;
    __syncthreads();

#pragma unroll
    for (int i = 0; i < EPT; ++i) {
        if (dsts[i] >= 0) {
            int k = k0 + t + i * 256;
            int b = dsts[i] >> BSH;
            int dl = dsts[i] & 63;
            int slot = atomicAdd(&B[b], 1);
            stage[slot] = make_int2((dl << 17) | ei[k], __float_as_int(eattr[k]));
        }
    }
    __syncthreads();

    for (int b = t; b < NB; b += 256) {
        int c0 = A[b], c1 = B[b];
        if (c1 > c0) B[b] = atomicAdd(&gcur[b], c1 - c0) - c0;
    }
    __syncthreads();

    int s0 = t * EPT;
    int lo = 0, hi = NB;
    while (hi - lo > 1) { int mid = (lo + hi) >> 1; if (A[mid] <= s0) lo = mid; else hi = mid; }
    int b = lo;
#pragma unroll
    for (int i = 0; i < EPT; ++i) {
        int sl = s0 + i;
        if (sl >= tot) break;
        while (sl >= A[b + 1]) ++b;
        bed[B[b] + sl] = stage[sl];
    }
}

// ---------------- per-bucket dl counting-sort -> exact per-node CSR ----------
__global__ __launch_bounds__(256) void dlsort_kernel(
    int2* __restrict__ bed, const int* __restrict__ off,
    int* __restrict__ nstart, int* __restrict__ nend, int N, int NB)
{
    __shared__ int2 stage[4096];
    __shared__ int hist[64], excl[65], cur[64];
    int t = threadIdx.x, b = blockIdx.x;
    int e0 = off[b], e1 = off[b + 1], cnt = e1 - e0;
    if (t < 64) hist[t] = 0;
    __syncthreads();

    if (cnt <= 4096) {
        for (int i = t; i < cnt; i += 256) {
            int2 r = bed[e0 + i];
            stage[i] = r;
            atomicAdd(&hist[(unsigned)r.x >> 17], 1);
        }
        __syncthreads();
        if (t == 0) {
            int s = 0;
#pragma unroll
            for (int i = 0; i < 64; ++i) { excl[i] = s; s += hist[i]; }
            excl[64] = s;
        }
        __syncthreads();
        if (t < 64) {
            cur[t] = excl[t];
            int n = b * 64 + t;
            if (n < N) { nstart[n] = e0 + excl[t]; nend[n] = e0 + excl[t + 1]; }
        }
        __syncthreads();
        for (int i = t; i < cnt; i += 256) {
            int2 r = stage[i];
            int p = atomicAdd(&cur[(unsigned)r.x >> 17], 1);
            bed[e0 + p] = r;
        }
    } else {
        int n = b * 64 + t;
        if (t < 64 && n < N) { nstart[n] = e0; nend[n] = e1; }
    }
}

// ---------------- gather: z[n] = h[n] + sum relu(h[src] + ea*ew + eb) ----
// wave per node, lane = channel, fp16 h rows (128B), scalar (SGPR) record
// loads via readfirstlane'd base, 8/4/1-deep ILP, register accumulation.
__global__ __launch_bounds__(256) void gather_kernel(
    const __half* __restrict__ h, const int2* __restrict__ bed,
    const int* __restrict__ nstart, const int* __restrict__ nend,
    const float* __restrict__ ew, const float* __restrict__ eb,
    float* __restrict__ z, int N)
{
    int lane = threadIdx.x & 63;
    int wid  = threadIdx.x >> 6;
    int n = blockIdx.x * 4 + wid;
    if (n >= N) return;
    float wj = ew[lane], bj = eb[lane];
    int e  = nstart[n];
    int e1 = nend[n];
    unsigned mydl = (unsigned)(n & 63);
    float acc = __half2float(h[(size_t)n * H + lane]);   // self term (eps = 0)

#define GREC(r, hv) \
    ((((unsigned)(r).x >> 17) == mydl) \
        ? fmaxf(fmaf(__int_as_float((r).y), wj, bj) + (hv), 0.f) : 0.f)

    for (; e + 8 <= e1; e += 8) {
        const int2* p = bed + __builtin_amdgcn_readfirstlane(e);
        int2 r0 = p[0], r1 = p[1], r2 = p[2], r3 = p[3];
        int2 r4 = p[4], r5 = p[5], r6 = p[6], r7 = p[7];
        float v0 = __half2float(h[(size_t)(r0.x & 0x1FFFF) * H + lane]);
        float v1 = __half2float(h[(size_t)(r1.x & 0x1FFFF) * H + lane]);
        float v2 = __half2float(h[(size_t)(r2.x & 0x1FFFF) * H + lane]);
        float v3 = __half2float(h[(size_t)(r3.x & 0x1FFFF) * H + lane]);
        float v4 = __half2float(h[(size_t)(r4.x & 0x1FFFF) * H + lane]);
        float v5 = __half2float(h[(size_t)(r5.x & 0x1FFFF) * H + lane]);
        float v6 = __half2float(h[(size_t)(r6.x & 0x1FFFF) * H + lane]);
        float v7 = __half2float(h[(size_t)(r7.x & 0x1FFFF) * H + lane]);
        acc += GREC(r0, v0) + GREC(r1, v1) + GREC(r2, v2) + GREC(r3, v3)
             + GREC(r4, v4) + GREC(r5, v5) + GREC(r6, v6) + GREC(r7, v7);
    }
    if (e + 4 <= e1) {
        const int2* p = bed + __builtin_amdgcn_readfirstlane(e);
        int2 r0 = p[0], r1 = p[1], r2 = p[2], r3 = p[3];
        float v0 = __half2float(h[(size_t)(r0.x & 0x1FFFF) * H + lane]);
        float v1 = __half2float(h[(size_t)(r1.x & 0x1FFFF) * H + lane]);
        float v2 = __half2float(h[(size_t)(r2.x & 0x1FFFF) * H + lane]);
        float v3 = __half2float(h[(size_t)(r3.x & 0x1FFFF) * H + lane]);
        acc += GREC(r0, v0) + GREC(r1, v1) + GREC(r2, v2) + GREC(r3, v3);
        e += 4;
    }
    for (; e < e1; ++e) {
        const int2* p = bed + __builtin_amdgcn_readfirstlane(e);
        int2 r = p[0];
        float v = __half2float(h[(size_t)(r.x & 0x1FFFF) * H + lane]);
        acc += GREC(r, v);
    }
#undef GREC
    z[(size_t)n * H + lane] = acc;
}

// ---------------- per 64-node tile MLP (z fp32 in, h fp16 out) ----------------
__global__ __launch_bounds__(256) void mlp_kernel(
    const float* __restrict__ z, const float* __restrict__ w1,
    const float* __restrict__ b1, const float* __restrict__ w2,
    const float* __restrict__ b2, __half* __restrict__ out, int N)
{
    __shared__ float zT[H * PAD];
    __shared__ float wS[H * PAD];
    int tid = threadIdx.x;
    int nb = blockIdx.x * 64;

    {
        int i  = tid >> 2;
        int jc = (tid & 3) * 16;
        const float4* s = (const float4*)(w1 + i * H + jc);
        float4* d = (float4*)(wS + i * PAD + jc);
        d[0] = s[0]; d[1] = s[1]; d[2] = s[2]; d[3] = s[3];
    }
    {
        int nl = tid >> 2;
        int n  = nb + nl;
        int ic = (tid & 3) * 16;
        if (n < N) {
#pragma unroll
            for (int m = 0; m < 4; ++m) {
                float4 zv = *(const float4*)(z + (size_t)n * H + ic + m * 4);
                zT[(ic + m * 4 + 0) * PAD + nl] = zv.x;
                zT[(ic + m * 4 + 1) * PAD + nl] = zv.y;
                zT[(ic + m * 4 + 2) * PAD + nl] = zv.z;
                zT[(ic + m * 4 + 3) * PAD + nl] = zv.w;
            }
        } else {
#pragma unroll
            for (int m = 0; m < 4; ++m)
#pragma unroll
                for (int q = 0; q < 4; ++q)
                    zT[(ic + m * 4 + q) * PAD + nl] = 0.f;
        }
    }
    __syncthreads();

    int tj = tid & 15, tn = tid >> 4;
    int j0 = tj * 4, n0 = tn * 4;

    float acc[4][4] = {};
#pragma unroll 4
    for (int i = 0; i < H; ++i) {
        float4 a = *(const float4*)(zT + i * PAD + n0);
        float4 b = *(const float4*)(wS + i * PAD + j0);
        float av[4] = {a.x, a.y, a.z, a.w};
        float bv[4] = {b.x, b.y, b.z, b.w};
#pragma unroll
        for (int p = 0; p < 4; ++p)
#pragma unroll
            for (int q = 0; q < 4; ++q)
                acc[p][q] = fmaf(av[p], bv[q], acc[p][q]);
    }
    float4 bb1 = *(const float4*)(b1 + j0);
    float u[4][4];
#pragma unroll
    for (int p = 0; p < 4; ++p) {
        u[p][0] = fmaxf(acc[p][0] + bb1.x, 0.f);
        u[p][1] = fmaxf(acc[p][1] + bb1.y, 0.f);
        u[p][2] = fmaxf(acc[p][2] + bb1.z, 0.f);
        u[p][3] = fmaxf(acc[p][3] + bb1.w, 0.f);
    }
    __syncthreads();

#pragma unroll
    for (int p = 0; p < 4; ++p)
#pragma unroll
        for (int q = 0; q < 4; ++q)
            zT[(j0 + q) * PAD + (n0 + p)] = u[p][q];
    {
        int i  = tid >> 2;
        int jc = (tid & 3) * 16;
        const float4* s = (const float4*)(w2 + i * H + jc);
        float4* d = (float4*)(wS + i * PAD + jc);
        d[0] = s[0]; d[1] = s[1]; d[2] = s[2]; d[3] = s[3];
    }
    __syncthreads();

    float acc2[4][4] = {};
#pragma unroll 4
    for (int i = 0; i < H; ++i) {
        float4 a = *(const float4*)(zT + i * PAD + n0);
        float4 b = *(const float4*)(wS + i * PAD + j0);
        float av[4] = {a.x, a.y, a.z, a.w};
        float bv[4] = {b.x, b.y, b.z, b.w};
#pragma unroll
        for (int p = 0; p < 4; ++p)
#pragma unroll
            for (int q = 0; q < 4; ++q)
                acc2[p][q] = fmaf(av[p], bv[q], acc2[p][q]);
    }
    float4 bb2 = *(const float4*)(b2 + j0);
#pragma unroll
    for (int p = 0; p < 4; ++p) {
        int n = nb + n0 + p;
        if (n < N) {
            uint2 r;
            r.x = pack2(fmaxf(acc2[p][0] + bb2.x, 0.f),
                        fmaxf(acc2[p][1] + bb2.y, 0.f));
            r.y = pack2(fmaxf(acc2[p][2] + bb2.z, 0.f),
                        fmaxf(acc2[p][3] + bb2.w, 0.f));
            *(uint2*)(out + (size_t)n * H + j0) = r;
        }
    }
}

// ---------------- mean pool (batch sorted): 4 waves/block, 64 nodes/wave ----
__global__ __launch_bounds__(256) void pool_kernel(
    const __half* __restrict__ h, const int* __restrict__ batch,
    float* __restrict__ sums, float* __restrict__ counts, int N)
{
    int lane = threadIdx.x & 63;
    int wid  = threadIdx.x >> 6;
    int start = blockIdx.x * 256 + wid * 64;
    if (start >= N) return;
    int end = start + 64; if (end > N) end = N;
    int cur = batch[start];
    float acc = 0.f;
    int cnt = 0;
    for (int n = start; n < end; ++n) {
        int g = batch[n];
        if (g != cur) {
            atomicAdd(sums + cur * H + lane, acc);
            if (lane == 0) atomicAdd(counts + cur, (float)cnt);
            acc = 0.f; cnt = 0; cur = g;
        }
        acc += __half2float(h[(size_t)n * H + lane]);
        cnt++;
    }
    atomicAdd(sums + cur * H + lane, acc);
    if (lane == 0) atomicAdd(counts + cur, (float)cnt);
}

__global__ void div_kernel(const float* __restrict__ sums,
                           const float* __restrict__ counts,
                           float* __restrict__ out)
{
    int g = blockIdx.x, j = threadIdx.x;
    out[g * H + j] = sums[g * H + j] / fmaxf(counts[g], 1.0f);
}

extern "C" void kernel_launch(void* const* d_in, const int* in_sizes, int n_in,
                              void* d_out, int out_size, void* d_ws, size_t ws_size,
                              hipStream_t stream)
{
    const float* x     = (const float*)d_in[0];
    const int*   ei    = (const int*)d_in[1];
    const float* eattr = (const float*)d_in[2];
    const int*   batch = (const int*)d_in[3];
    const float* ne_w  = (const float*)d_in[4];
    const float* ne_b  = (const float*)d_in[5];
    const float* ee_w  = (const float*)d_in[6];
    const float* ee_b  = (const float*)d_in[7];
    const float* c1w1  = (const float*)d_in[8];
    const float* c1b1  = (const float*)d_in[9];
    const float* c1w2  = (const float*)d_in[10];
    const float* c1b2  = (const float*)d_in[11];
    const float* c2w1  = (const float*)d_in[12];
    const float* c2b1  = (const float*)d_in[13];
    const float* c2w2  = (const float*)d_in[14];
    const float* c2b2  = (const float*)d_in[15];

    const int N = in_sizes[0];
    const int E = in_sizes[2];
    const int NB = (N + 63) >> BSH;

    // ---- workspace (byte carve, 16B-aligned sections) ----
    char* w = (char*)d_ws;
    __half* h   = (__half*)w;            w += (size_t)N * H * sizeof(__half);
    float* z    = (float*)w;             w += (size_t)N * H * sizeof(float);
    float* sums = (float*)w;             w += 64 * H * sizeof(float);
    float* counts = (float*)w;           w += 64 * sizeof(float);
    int* ghist  = (int*)w;               w += (size_t)NB * sizeof(int);
    int* off    = (int*)w;               w += (size_t)(NB + 1) * sizeof(int);
    int* gcur   = (int*)w;               w += (size_t)NB * sizeof(int);
    int* nstart = (int*)w;               w += (size_t)N * sizeof(int);
    int* nend   = (int*)w;               w += (size_t)N * sizeof(int);
    uintptr_t p = ((uintptr_t)w + 15) & ~(uintptr_t)15;
    int2* bed   = (int2*)p;              // E records

    const int eGrid = (E + EPB - 1) / EPB;
    const int mlpGrid = (N + 63) / 64;

    size_t histLds = (size_t)NB * sizeof(int);
    size_t scatLds = (size_t)(2 * EPB + (NB + 1) + NB + 256) * sizeof(int);

    encode_kernel<<<(N * 16 + 255) / 256, 256, 0, stream>>>(x, ne_w, ne_b, h, N);

    // ---- bucket build + exact CSR (once, reused by both layers) ----
    hipMemsetAsync(ghist, 0, (size_t)NB * sizeof(int), stream);
    bhist_kernel<<<eGrid, 256, histLds, stream>>>(ei, ghist, E, NB);
    bscan_kernel<<<1, 256, 0, stream>>>(ghist, off, gcur, NB);
    binscatter_kernel<<<eGrid, 256, scatLds, stream>>>(ei, eattr, gcur, bed, E, NB);
    dlsort_kernel<<<NB, 256, 0, stream>>>(bed, off, nstart, nend, N, NB);

    const int gatherGrid = (N + 3) / 4;

    // ---- layer 1 ----
    gather_kernel<<<gatherGrid, 256, 0, stream>>>(h, bed, nstart, nend, ee_w, ee_b, z, N);
    mlp_kernel<<<mlpGrid, 256, 0, stream>>>(z, c1w1, c1b1, c1w2, c1b2, h, N);

    // ---- layer 2 ----
    gather_kernel<<<gatherGrid, 256, 0, stream>>>(h, bed, nstart, nend, ee_w, ee_b, z, N);
    mlp_kernel<<<mlpGrid, 256, 0, stream>>>(z, c2w1, c2b1, c2w2, c2b2, h, N);

    // ---- mean pool ----
    hipMemsetAsync(sums, 0, (64 * H + 64) * sizeof(float), stream);
    pool_kernel<<<(N + 255) / 256, 256, 0, stream>>>(h, batch, sums, counts, N);
    div_kernel<<<64, 64, 0, stream>>>(sums, counts, (float*)d_out);
}

// Round 8
// 242.645 us; speedup vs baseline: 4.4869x; 1.0013x over previous
//
#include <hip/hip_runtime.h>
#include <hip/hip_fp16.h>

constexpr int H = 64;
constexpr int PAD = 68;     // LDS row stride (floats) for MLP tiles
constexpr int BSH = 6;      // 64 nodes per bucket
constexpr int EPB = 4096;   // edges per binning block
constexpr int EPT = EPB / 256;  // 16 edges per thread

__device__ inline unsigned pack2(float a, float b) {
    __half2 hh = __floats2half2_rn(a, b);
    return *(unsigned*)&hh;
}

// ---------------- zero: one tiny kernel replaces hipMemsetAsync (41us each!) --
__global__ __launch_bounds__(256) void zero_kernel(unsigned* __restrict__ p, int n)
{
    int i = blockIdx.x * 256 + threadIdx.x;
    if (i < n) p[i] = 0u;
}

// ---------------- encode: h16[n][j] = x[n] * ne_w[j] + ne_b[j] ----------------
__global__ __launch_bounds__(256) void encode_kernel(
    const float* __restrict__ x, const float* __restrict__ nw,
    const float* __restrict__ nb, __half* __restrict__ hout, int N)
{
    int idx = blockIdx.x * 256 + threadIdx.x;        // over N*16 groups of 4ch
    if (idx >= N * 16) return;
    int n = idx >> 4, c = idx & 15;
    float xv = x[n];
    float4 w = ((const float4*)nw)[c];
    float4 b = ((const float4*)nb)[c];
    uint2 r;
    r.x = pack2(fmaf(xv, w.x, b.x), fmaf(xv, w.y, b.y));
    r.y = pack2(fmaf(xv, w.z, b.z), fmaf(xv, w.w, b.w));
    ((uint2*)hout)[idx] = r;
}

// ---------------- bucket histogram (LDS-aggregated) ----------------
__global__ __launch_bounds__(256) void bhist_kernel(
    const int* __restrict__ ei, int* __restrict__ ghist, int E, int NB)
{
    extern __shared__ int lh[];               // NB ints
    for (int b = threadIdx.x; b < NB; b += 256) lh[b] = 0;
    __syncthreads();
    int k0 = blockIdx.x * EPB;
#pragma unroll
    for (int i = 0; i < EPT; ++i) {
        int k = k0 + threadIdx.x + i * 256;
        if (k < E) atomicAdd(&lh[ei[E + k] >> BSH], 1);
    }
    __syncthreads();
    for (int b = threadIdx.x; b < NB; b += 256)
        if (lh[b]) atomicAdd(&ghist[b], lh[b]);
}

// ---------------- single-block exclusive scan; also seeds gcur ----------------
__global__ __launch_bounds__(256) void bscan_kernel(
    const int* __restrict__ ghist, int* __restrict__ off,
    int* __restrict__ gcur, int NB)
{
    __shared__ int part[256];
    int t = threadIdx.x;
    const int C = (NB + 255) / 256;
    int loc[16];
    int s = 0;
    for (int j = 0; j < C; ++j) {
        int idx = t * C + j;
        int v = (idx < NB) ? ghist[idx] : 0;
        loc[j] = s; s += v;
    }
    part[t] = s;
    __syncthreads();
    for (int d = 1; d < 256; d <<= 1) {
        int x = (t >= d) ? part[t - d] : 0;
        __syncthreads();
        part[t] += x;
        __syncthreads();
    }
    int base = part[t] - s;
    for (int j = 0; j < C; ++j) {
        int idx = t * C + j;
        if (idx < NB) { int v = base + loc[j]; off[idx] = v; gcur[idx] = v; }
    }
    if (t == 255) off[NB] = part[255];
}

// ---------------- block-aggregated bin scatter ----------------
// Record: (dstLocal<<17 | src, ea) -- src < 2^17, dl < 64.
__global__ __launch_bounds__(256) void binscatter_kernel(
    const int* __restrict__ ei, const float* __restrict__ eattr,
    int* __restrict__ gcur, int2* __restrict__ bed, int E, int NB)
{
    extern __shared__ int smem[];
    int2* stage = (int2*)smem;                // EPB int2
    int*  A     = smem + 2 * EPB;             // NB+1
    int*  B     = A + NB + 1;                 // NB
    int*  part  = B + NB;                     // 256
    int t = threadIdx.x;
    int k0 = blockIdx.x * EPB;

    for (int b = t; b < NB + 1; b += 256) A[b] = 0;
    __syncthreads();

    int dsts[EPT];
#pragma unroll
    for (int i = 0; i < EPT; ++i) {
        int k = k0 + t + i * 256;
        dsts[i] = (k < E) ? ei[E + k] : -1;
        if (dsts[i] >= 0) atomicAdd(&A[dsts[i] >> BSH], 1);
    }
    __syncthreads();

    const int C = (NB + 255) / 256;
    int loc[16];
    int s = 0;
    for (int j = 0; j < C; ++j) {
        int idx = t * C + j;
        int v = (idx < NB) ? A[idx] : 0;
        loc[j] = s; s += v;
    }
    part[t] = s;
    __syncthreads();
    for (int d = 1; d < 256; d <<= 1) {
        int x = (t >= d) ? part[t - d] : 0;
        __syncthreads();
        part[t] += x;
        __syncthreads();
    }
    int base = part[t] - s;
    int tot = part[255];
    for (int j = 0; j < C; ++j) {
        int idx = t * C + j;
        if (idx < NB) { int e = base + loc[j]; A[idx] = e; B[idx] = e; }
    }
    if (t == 255) A[NB] = tot;
    __syncthreads();

#pragma unroll
    for (int i = 0; i < EPT; ++i) {
        if (dsts[i] >= 0) {
            int k = k0 + t + i * 256;
            int b = dsts[i] >> BSH;
            int dl = dsts[i] & 63;
            int slot = atomicAdd(&B[b], 1);
            stage[slot] = make_int2((dl << 17) | ei[k], __float_as_int(eattr[k]));
        }
    }
    __syncthreads();

    for (int b = t; b < NB; b += 256) {
        int c0 = A[b], c1 = B[b];
        if (c1 > c0) B[b] = atomicAdd(&gcur[b], c1 - c0) - c0;
    }
    __syncthreads();

    int s0 = t * EPT;
    int lo = 0, hi = NB;
    while (hi - lo > 1) { int mid = (lo + hi) >> 1; if (A[mid] <= s0) lo = mid; else hi = mid; }
    int b = lo;
#pragma unroll
    for (int i = 0; i < EPT; ++i) {
        int sl = s0 + i;
        if (sl >= tot) break;
        while (sl >= A[b + 1]) ++b;
        bed[B[b] + sl] = stage[sl];
    }
}

// ---------------- per-bucket dl counting-sort -> exact per-node CSR ----------
__global__ __launch_bounds__(256) void dlsort_kernel(
    int2* __restrict__ bed, const int* __restrict__ off,
    int* __restrict__ nstart, int* __restrict__ nend, int N, int NB)
{
    __shared__ int2 stage[4096];
    __shared__ int hist[64], excl[65], cur[64];
    int t = threadIdx.x, b = blockIdx.x;
    int e0 = off[b], e1 = off[b + 1], cnt = e1 - e0;
    if (t < 64) hist[t] = 0;
    __syncthreads();

    if (cnt <= 4096) {
        for (int i = t; i < cnt; i += 256) {
            int2 r = bed[e0 + i];
            stage[i] = r;
            atomicAdd(&hist[(unsigned)r.x >> 17], 1);
        }
        __syncthreads();
        if (t == 0) {
            int s = 0;
#pragma unroll
            for (int i = 0; i < 64; ++i) { excl[i] = s; s += hist[i]; }
            excl[64] = s;
        }
        __syncthreads();
        if (t < 64) {
            cur[t] = excl[t];
            int n = b * 64 + t;
            if (n < N) { nstart[n] = e0 + excl[t]; nend[n] = e0 + excl[t + 1]; }
        }
        __syncthreads();
        for (int i = t; i < cnt; i += 256) {
            int2 r = stage[i];
            int p = atomicAdd(&cur[(unsigned)r.x >> 17], 1);
            bed[e0 + p] = r;
        }
    } else {
        int n = b * 64 + t;
        if (t < 64 && n < N) { nstart[n] = e0; nend[n] = e1; }
    }
}

// ---------------- gather: z[n] = h[n] + sum relu(h[src] + ea*ew + eb) ----
// wave per node, lane = channel, fp16 h rows (128B), scalar (SGPR) record
// loads via readfirstlane'd base, 8/4/1-deep ILP, register accumulation.
__global__ __launch_bounds__(256) void gather_kernel(
    const __half* __restrict__ h, const int2* __restrict__ bed,
    const int* __restrict__ nstart, const int* __restrict__ nend,
    const float* __restrict__ ew, const float* __restrict__ eb,
    float* __restrict__ z, int N)
{
    int lane = threadIdx.x & 63;
    int wid  = threadIdx.x >> 6;
    int n = blockIdx.x * 4 + wid;
    if (n >= N) return;
    float wj = ew[lane], bj = eb[lane];
    int e  = nstart[n];
    int e1 = nend[n];
    unsigned mydl = (unsigned)(n & 63);
    float acc = __half2float(h[(size_t)n * H + lane]);   // self term (eps = 0)

#define GREC(r, hv) \
    ((((unsigned)(r).x >> 17) == mydl) \
        ? fmaxf(fmaf(__int_as_float((r).y), wj, bj) + (hv), 0.f) : 0.f)

    for (; e + 8 <= e1; e += 8) {
        const int2* p = bed + __builtin_amdgcn_readfirstlane(e);
        int2 r0 = p[0], r1 = p[1], r2 = p[2], r3 = p[3];
        int2 r4 = p[4], r5 = p[5], r6 = p[6], r7 = p[7];
        float v0 = __half2float(h[(size_t)(r0.x & 0x1FFFF) * H + lane]);
        float v1 = __half2float(h[(size_t)(r1.x & 0x1FFFF) * H + lane]);
        float v2 = __half2float(h[(size_t)(r2.x & 0x1FFFF) * H + lane]);
        float v3 = __half2float(h[(size_t)(r3.x & 0x1FFFF) * H + lane]);
        float v4 = __half2float(h[(size_t)(r4.x & 0x1FFFF) * H + lane]);
        float v5 = __half2float(h[(size_t)(r5.x & 0x1FFFF) * H + lane]);
        float v6 = __half2float(h[(size_t)(r6.x & 0x1FFFF) * H + lane]);
        float v7 = __half2float(h[(size_t)(r7.x & 0x1FFFF) * H + lane]);
        acc += GREC(r0, v0) + GREC(r1, v1) + GREC(r2, v2) + GREC(r3, v3)
             + GREC(r4, v4) + GREC(r5, v5) + GREC(r6, v6) + GREC(r7, v7);
    }
    if (e + 4 <= e1) {
        const int2* p = bed + __builtin_amdgcn_readfirstlane(e);
        int2 r0 = p[0], r1 = p[1], r2 = p[2], r3 = p[3];
        float v0 = __half2float(h[(size_t)(r0.x & 0x1FFFF) * H + lane]);
        float v1 = __half2float(h[(size_t)(r1.x & 0x1FFFF) * H + lane]);
        float v2 = __half2float(h[(size_t)(r2.x & 0x1FFFF) * H + lane]);
        float v3 = __half2float(h[(size_t)(r3.x & 0x1FFFF) * H + lane]);
        acc += GREC(r0, v0) + GREC(r1, v1) + GREC(r2, v2) + GREC(r3, v3);
        e += 4;
    }
    for (; e < e1; ++e) {
        const int2* p = bed + __builtin_amdgcn_readfirstlane(e);
        int2 r = p[0];
        float v = __half2float(h[(size_t)(r.x & 0x1FFFF) * H + lane]);
        acc += GREC(r, v);
    }
#undef GREC
    z[(size_t)n * H + lane] = acc;
}

// ---------------- per 64-node tile MLP (z fp32 in, h fp16 out) ----------------
__global__ __launch_bounds__(256) void mlp_kernel(
    const float* __restrict__ z, const float* __restrict__ w1,
    const float* __restrict__ b1, const float* __restrict__ w2,
    const float* __restrict__ b2, __half* __restrict__ out, int N)
{
    __shared__ float zT[H * PAD];
    __shared__ float wS[H * PAD];
    int tid = threadIdx.x;
    int nb = blockIdx.x * 64;

    {
        int i  = tid >> 2;
        int jc = (tid & 3) * 16;
        const float4* s = (const float4*)(w1 + i * H + jc);
        float4* d = (float4*)(wS + i * PAD + jc);
        d[0] = s[0]; d[1] = s[1]; d[2] = s[2]; d[3] = s[3];
    }
    {
        int nl = tid >> 2;
        int n  = nb + nl;
        int ic = (tid & 3) * 16;
        if (n < N) {
#pragma unroll
            for (int m = 0; m < 4; ++m) {
                float4 zv = *(const float4*)(z + (size_t)n * H + ic + m * 4);
                zT[(ic + m * 4 + 0) * PAD + nl] = zv.x;
                zT[(ic + m * 4 + 1) * PAD + nl] = zv.y;
                zT[(ic + m * 4 + 2) * PAD + nl] = zv.z;
                zT[(ic + m * 4 + 3) * PAD + nl] = zv.w;
            }
        } else {
#pragma unroll
            for (int m = 0; m < 4; ++m)
#pragma unroll
                for (int q = 0; q < 4; ++q)
                    zT[(ic + m * 4 + q) * PAD + nl] = 0.f;
        }
    }
    __syncthreads();

    int tj = tid & 15, tn = tid >> 4;
    int j0 = tj * 4, n0 = tn * 4;

    float acc[4][4] = {};
#pragma unroll 4
    for (int i = 0; i < H; ++i) {
        float4 a = *(const float4*)(zT + i * PAD + n0);
        float4 b = *(const float4*)(wS + i * PAD + j0);
        float av[4] = {a.x, a.y, a.z, a.w};
        float bv[4] = {b.x, b.y, b.z, b.w};
#pragma unroll
        for (int p = 0; p < 4; ++p)
#pragma unroll
            for (int q = 0; q < 4; ++q)
                acc[p][q] = fmaf(av[p], bv[q], acc[p][q]);
    }
    float4 bb1 = *(const float4*)(b1 + j0);
    float u[4][4];
#pragma unroll
    for (int p = 0; p < 4; ++p) {
        u[p][0] = fmaxf(acc[p][0] + bb1.x, 0.f);
        u[p][1] = fmaxf(acc[p][1] + bb1.y, 0.f);
        u[p][2] = fmaxf(acc[p][2] + bb1.z, 0.f);
        u[p][3] = fmaxf(acc[p][3] + bb1.w, 0.f);
    }
    __syncthreads();

#pragma unroll
    for (int p = 0; p < 4; ++p)
#pragma unroll
        for (int q = 0; q < 4; ++q)
            zT[(j0 + q) * PAD + (n0 + p)] = u[p][q];
    {
        int i  = tid >> 2;
        int jc = (tid & 3) * 16;
        const float4* s = (const float4*)(w2 + i * H + jc);
        float4* d = (float4*)(wS + i * PAD + jc);
        d[0] = s[0]; d[1] = s[1]; d[2] = s[2]; d[3] = s[3];
    }
    __syncthreads();

    float acc2[4][4] = {};
#pragma unroll 4
    for (int i = 0; i < H; ++i) {
        float4 a = *(const float4*)(zT + i * PAD + n0);
        float4 b = *(const float4*)(wS + i * PAD + j0);
        float av[4] = {a.x, a.y, a.z, a.w};
        float bv[4] = {b.x, b.y, b.z, b.w};
#pragma unroll
        for (int p = 0; p < 4; ++p)
#pragma unroll
            for (int q = 0; q < 4; ++q)
                acc2[p][q] = fmaf(av[p], bv[q], acc2[p][q]);
    }
    float4 bb2 = *(const float4*)(b2 + j0);
#pragma unroll
    for (int p = 0; p < 4; ++p) {
        int n = nb + n0 + p;
        if (n < N) {
            uint2 r;
            r.x = pack2(fmaxf(acc2[p][0] + bb2.x, 0.f),
                        fmaxf(acc2[p][1] + bb2.y, 0.f));
            r.y = pack2(fmaxf(acc2[p][2] + bb2.z, 0.f),
                        fmaxf(acc2[p][3] + bb2.w, 0.f));
            *(uint2*)(out + (size_t)n * H + j0) = r;
        }
    }
}

// ---------------- mean pool (batch sorted): 4 waves/block, 64 nodes/wave ----
__global__ __launch_bounds__(256) void pool_kernel(
    const __half* __restrict__ h, const int* __restrict__ batch,
    float* __restrict__ sums, float* __restrict__ counts, int N)
{
    int lane = threadIdx.x & 63;
    int wid  = threadIdx.x >> 6;
    int start = blockIdx.x * 256 + wid * 64;
    if (start >= N) return;
    int end = start + 64; if (end > N) end = N;
    int cur = batch[start];
    float acc = 0.f;
    int cnt = 0;
    for (int n = start; n < end; ++n) {
        int g = batch[n];
        if (g != cur) {
            atomicAdd(sums + cur * H + lane, acc);
            if (lane == 0) atomicAdd(counts + cur, (float)cnt);
            acc = 0.f; cnt = 0; cur = g;
        }
        acc += __half2float(h[(size_t)n * H + lane]);
        cnt++;
    }
    atomicAdd(sums + cur * H + lane, acc);
    if (lane == 0) atomicAdd(counts + cur, (float)cnt);
}

__global__ void div_kernel(const float* __restrict__ sums,
                           const float* __restrict__ counts,
                           float* __restrict__ out)
{
    int g = blockIdx.x, j = threadIdx.x;
    out[g * H + j] = sums[g * H + j] / fmaxf(counts[g], 1.0f);
}

extern "C" void kernel_launch(void* const* d_in, const int* in_sizes, int n_in,
                              void* d_out, int out_size, void* d_ws, size_t ws_size,
                              hipStream_t stream)
{
    const float* x     = (const float*)d_in[0];
    const int*   ei    = (const int*)d_in[1];
    const float* eattr = (const float*)d_in[2];
    const int*   batch = (const int*)d_in[3];
    const float* ne_w  = (const float*)d_in[4];
    const float* ne_b  = (const float*)d_in[5];
    const float* ee_w  = (const float*)d_in[6];
    const float* ee_b  = (const float*)d_in[7];
    const float* c1w1  = (const float*)d_in[8];
    const float* c1b1  = (const float*)d_in[9];
    const float* c1w2  = (const float*)d_in[10];
    const float* c1b2  = (const float*)d_in[11];
    const float* c2w1  = (const float*)d_in[12];
    const float* c2b1  = (const float*)d_in[13];
    const float* c2w2  = (const float*)d_in[14];
    const float* c2b2  = (const float*)d_in[15];

    const int N = in_sizes[0];
    const int E = in_sizes[2];
    const int NB = (N + 63) >> BSH;

    // ---- workspace (byte carve; sums/counts/ghist contiguous for one zero) ----
    char* w = (char*)d_ws;
    __half* h   = (__half*)w;            w += (size_t)N * H * sizeof(__half);
    float* z    = (float*)w;             w += (size_t)N * H * sizeof(float);
    float* sums = (float*)w;             w += 64 * H * sizeof(float);
    float* counts = (float*)w;           w += 64 * sizeof(float);
    int* ghist  = (int*)w;               w += (size_t)NB * sizeof(int);
    int* off    = (int*)w;               w += (size_t)(NB + 1) * sizeof(int);
    int* gcur   = (int*)w;               w += (size_t)NB * sizeof(int);
    int* nstart = (int*)w;               w += (size_t)N * sizeof(int);
    int* nend   = (int*)w;               w += (size_t)N * sizeof(int);
    uintptr_t p = ((uintptr_t)w + 15) & ~(uintptr_t)15;
    int2* bed   = (int2*)p;              // E records

    const int eGrid = (E + EPB - 1) / EPB;
    const int mlpGrid = (N + 63) / 64;

    size_t histLds = (size_t)NB * sizeof(int);
    size_t scatLds = (size_t)(2 * EPB + (NB + 1) + NB + 256) * sizeof(int);

    // zero sums+counts+ghist in one tiny kernel (replaces two 41us runtime fills)
    const int zeroN = 64 * H + 64 + NB;
    zero_kernel<<<(zeroN + 255) / 256, 256, 0, stream>>>((unsigned*)sums, zeroN);

    encode_kernel<<<(N * 16 + 255) / 256, 256, 0, stream>>>(x, ne_w, ne_b, h, N);

    // ---- bucket build + exact CSR (once, reused by both layers) ----
    bhist_kernel<<<eGrid, 256, histLds, stream>>>(ei, ghist, E, NB);
    bscan_kernel<<<1, 256, 0, stream>>>(ghist, off, gcur, NB);
    binscatter_kernel<<<eGrid, 256, scatLds, stream>>>(ei, eattr, gcur, bed, E, NB);
    dlsort_kernel<<<NB, 256, 0, stream>>>(bed, off, nstart, nend, N, NB);

    const int gatherGrid = (N + 3) / 4;

    // ---- layer 1 ----
    gather_kernel<<<gatherGrid, 256, 0, stream>>>(h, bed, nstart, nend, ee_w, ee_b, z, N);
    mlp_kernel<<<mlpGrid, 256, 0, stream>>>(z, c1w1, c1b1, c1w2, c1b2, h, N);

    // ---- layer 2 ----
    gather_kernel<<<gatherGrid, 256, 0, stream>>>(h, bed, nstart, nend, ee_w, ee_b, z, N);
    mlp_kernel<<<mlpGrid, 256, 0, stream>>>(z, c2w1, c2b1, c2w2, c2b2, h, N);

    // ---- mean pool ----
    pool_kernel<<<(N + 255) / 256, 256, 0, stream>>>(h, batch, sums, counts, N);
    div_kernel<<<64, 64, 0, stream>>>(sums, counts, (float*)d_out);
}